// Round 15
// baseline (3332.492 us; speedup 1.0000x reference)
//
#include <hip/hip_runtime.h>
#include <math.h>
#include <stdio.h>
#include <stdint.h>

#define NH 256
#define NH3 768
#define FNODE 133
#define FEDGE 7
#define LDW_GATE1 263   // H + F_EDGE
#define NGRAPH 4096
#define NTASK 12
#define SLOPE 0.01f
#define CHUNK 34000
#define PADK 40         // f16 elems per LDS row: 32 + 8 pad (80B stride, 16B aligned)
#define KPAD_X 160      // x padded K (133 -> 160)
#define LDC2 512        // interleaved node-state row stride (f16): [tmp | xcur]
#define SCAN_TILE 2048

typedef __attribute__((ext_vector_type(4))) float f32x4;
typedef __attribute__((ext_vector_type(8))) _Float16 f16x8;
typedef __attribute__((ext_vector_type(4))) _Float16 f16x4;
typedef __attribute__((ext_vector_type(2))) _Float16 f16x2;

static __device__ __forceinline__ float lrelu_f(float x) { return x > 0.f ? x : SLOPE * x; }
static __device__ __forceinline__ f16x2 lrelu2(f16x2 v) {
    f16x2 z = {(_Float16)0.f, (_Float16)0.f};
    f16x2 s = {(_Float16)SLOPE, (_Float16)SLOPE};
    return __builtin_elementwise_max(v, z) + __builtin_elementwise_min(v, z) * s;
}

// ============ pipelined f16-weight GEMM core (BM=64, BN=256, depth-2 prefetch) ============
template<int ACT>
static __device__ __forceinline__ void gemm16_core(
    _Float16* As, _Float16* Ws,
    const _Float16* __restrict__ A, const _Float16* __restrict__ Wf,
    const float* __restrict__ bias, const float* __restrict__ bias2,
    _Float16* __restrict__ Cout,
    int M, int K, int ldA, int ldC, int ocol)
{
    const int bm = blockIdx.y * 64;
    const int tid = threadIdx.x;
    const int wv = tid >> 6, lane = tid & 63;
    const int l15 = lane & 15, l4 = lane >> 4;
    const int ar = tid >> 2, akq = (tid & 3) * 8;
    const int ga = bm + ar;

    f16x8 a0, w00, w01, w02, w03;   // tile set 0
    f16x8 a1, w10, w11, w12, w13;   // tile set 1
    auto load0 = [&](int k0) {
        if (ga < M) a0 = *reinterpret_cast<const f16x8*>(A + (size_t)ga * ldA + k0 + akq);
        else { f16x8 z = {}; a0 = z; }
        w00 = *reinterpret_cast<const f16x8*>(Wf + (size_t)ar * K + k0 + akq);
        w01 = *reinterpret_cast<const f16x8*>(Wf + (size_t)(ar + 64) * K + k0 + akq);
        w02 = *reinterpret_cast<const f16x8*>(Wf + (size_t)(ar + 128) * K + k0 + akq);
        w03 = *reinterpret_cast<const f16x8*>(Wf + (size_t)(ar + 192) * K + k0 + akq);
    };
    auto load1 = [&](int k0) {
        if (ga < M) a1 = *reinterpret_cast<const f16x8*>(A + (size_t)ga * ldA + k0 + akq);
        else { f16x8 z = {}; a1 = z; }
        w10 = *reinterpret_cast<const f16x8*>(Wf + (size_t)ar * K + k0 + akq);
        w11 = *reinterpret_cast<const f16x8*>(Wf + (size_t)(ar + 64) * K + k0 + akq);
        w12 = *reinterpret_cast<const f16x8*>(Wf + (size_t)(ar + 128) * K + k0 + akq);
        w13 = *reinterpret_cast<const f16x8*>(Wf + (size_t)(ar + 192) * K + k0 + akq);
    };
    auto stage0 = [&]() {
        *reinterpret_cast<f16x8*>(&As[ar * PADK + akq]) = a0;
        *reinterpret_cast<f16x8*>(&Ws[ar * PADK + akq]) = w00;
        *reinterpret_cast<f16x8*>(&Ws[(ar + 64) * PADK + akq]) = w01;
        *reinterpret_cast<f16x8*>(&Ws[(ar + 128) * PADK + akq]) = w02;
        *reinterpret_cast<f16x8*>(&Ws[(ar + 192) * PADK + akq]) = w03;
    };
    auto stage1 = [&]() {
        *reinterpret_cast<f16x8*>(&As[ar * PADK + akq]) = a1;
        *reinterpret_cast<f16x8*>(&Ws[ar * PADK + akq]) = w10;
        *reinterpret_cast<f16x8*>(&Ws[(ar + 64) * PADK + akq]) = w11;
        *reinterpret_cast<f16x8*>(&Ws[(ar + 128) * PADK + akq]) = w12;
        *reinterpret_cast<f16x8*>(&Ws[(ar + 192) * PADK + akq]) = w13;
    };

    f32x4 acc[16];
#pragma unroll
    for (int c = 0; c < 16; ++c) acc[c] = (f32x4){0.f, 0.f, 0.f, 0.f};

    auto mmac = [&]() {
        f16x8 af = *reinterpret_cast<const f16x8*>(&As[(wv * 16 + l15) * PADK + l4 * 8]);
#pragma unroll
        for (int c = 0; c < 16; ++c) {
            f16x8 wf = *reinterpret_cast<const f16x8*>(&Ws[(c * 16 + l15) * PADK + l4 * 8]);
            acc[c] = __builtin_amdgcn_mfma_f32_16x16x32_f16(af, wf, acc[c], 0, 0, 0);
        }
    };

    load0(0);
    if (K > 32) load1(32);
    for (int k0 = 0; k0 < K; k0 += 64) {
        stage0();
        __syncthreads();
        if (k0 + 64 < K) load0(k0 + 64);
        mmac();
        __syncthreads();
        if (k0 + 32 >= K) break;
        stage1();
        __syncthreads();
        if (k0 + 96 < K) load1(k0 + 96);
        mmac();
        __syncthreads();
    }

#pragma unroll
    for (int c = 0; c < 16; ++c) {
        int gc = c * 16 + l15;
        float bv = (bias ? bias[gc] : 0.f) + (bias2 ? bias2[gc] : 0.f);
#pragma unroll
        for (int q = 0; q < 4; ++q) {
            int gr = bm + wv * 16 + l4 * 4 + q;
            if (gr >= M) continue;
            float v = acc[c][q] + bv;
            if (ACT == 1) v = lrelu_f(v);
            else if (ACT == 2) v = (v > 0.f ? v : expm1f(v));
            else if (ACT == 3) v = 1.f / (1.f + expf(-v));
            Cout[(size_t)gr * ldC + ocol + gc] = (_Float16)v;
        }
    }
}

template<int ACT>
__global__ __launch_bounds__(256, 3) void gemm16(
    const _Float16* __restrict__ A, const _Float16* __restrict__ Wf,
    const float* __restrict__ bias, _Float16* __restrict__ Cout,
    int M, int K, int ldA, int ldC, int ocol)
{
    __shared__ _Float16 As[64 * PADK];
    __shared__ _Float16 Ws[256 * PADK];
    gemm16_core<ACT>(As, Ws, A, Wf, bias, nullptr, Cout, M, K, ldA, ldC, ocol);
}

// GRU launch A (merged): z=0 -> srz = sigmoid(Acat @ wcat16^T + bih + bhh) over ALL 512 cols
// (one A read feeds r AND z); z=1 -> inn = tmp @ wihn16^T + bih_n
__global__ __launch_bounds__(256, 2) void gemm_gru_rzi16(
    const _Float16* __restrict__ Acat, const _Float16* __restrict__ wcat16,
    const _Float16* __restrict__ wihn16,
    const float* __restrict__ bih, const float* __restrict__ bhh,
    _Float16* __restrict__ srz, _Float16* __restrict__ innb, int mc)
{
    __shared__ _Float16 As[64 * PADK];
    __shared__ _Float16 Ws[512 * PADK];
    if (blockIdx.z == 1) {
        gemm16_core<0>(As, Ws, Acat, wihn16, bih + 512, nullptr, innb, mc, 256, LDC2, 256, 0);
        return;
    }
    const int bm = blockIdx.y * 64;
    const int tid = threadIdx.x;
    const int wv = tid >> 6, lane = tid & 63;
    const int l15 = lane & 15, l4 = lane >> 4;
    const int ar = tid >> 2, akq = (tid & 3) * 8;
    const int ga = bm + ar;

    f16x8 ra, rw[8];
    auto loadT = [&](int k0) {
        if (ga < mc) ra = *reinterpret_cast<const f16x8*>(Acat + (size_t)ga * LDC2 + k0 + akq);
        else { f16x8 z = {}; ra = z; }
#pragma unroll
        for (int q = 0; q < 8; ++q)
            rw[q] = *reinterpret_cast<const f16x8*>(wcat16 + (size_t)(ar + 64 * q) * 512 + k0 + akq);
    };

    f32x4 acc[32];
#pragma unroll
    for (int c = 0; c < 32; ++c) acc[c] = (f32x4){0.f, 0.f, 0.f, 0.f};

    loadT(0);
    for (int k0 = 0; k0 < 512; k0 += 32) {
        *reinterpret_cast<f16x8*>(&As[ar * PADK + akq]) = ra;
#pragma unroll
        for (int q = 0; q < 8; ++q)
            *reinterpret_cast<f16x8*>(&Ws[(ar + 64 * q) * PADK + akq]) = rw[q];
        __syncthreads();
        if (k0 + 32 < 512) loadT(k0 + 32);
        f16x8 af = *reinterpret_cast<const f16x8*>(&As[(wv * 16 + l15) * PADK + l4 * 8]);
#pragma unroll
        for (int c = 0; c < 32; ++c) {
            f16x8 wf = *reinterpret_cast<const f16x8*>(&Ws[(c * 16 + l15) * PADK + l4 * 8]);
            acc[c] = __builtin_amdgcn_mfma_f32_16x16x32_f16(af, wf, acc[c], 0, 0, 0);
        }
        __syncthreads();
    }

#pragma unroll
    for (int c = 0; c < 32; ++c) {
        int gc = c * 16 + l15;
        float bv = bih[gc] + bhh[gc];
#pragma unroll
        for (int q = 0; q < 4; ++q) {
            int gr = bm + wv * 16 + l4 * 4 + q;
            if (gr >= mc) continue;
            float v = 1.f / (1.f + expf(-(acc[c][q] + bv)));
            srz[(size_t)gr * 512 + gc] = (_Float16)v;
        }
    }
}

// GRU launch B: hn GEMM + in-epilogue GRU combine + ReLU (xcur in place) + fused dots
__global__ __launch_bounds__(256, 4) void gemm_gru_b16(
    _Float16* __restrict__ Acat, const _Float16* __restrict__ Wn16, const float* __restrict__ bhh,
    const _Float16* __restrict__ srz, const _Float16* __restrict__ innb,
    const float* __restrict__ us, const float* __restrict__ ud,
    float* __restrict__ dotr, float* __restrict__ adst, int mc)
{
    __shared__ _Float16 As[64 * PADK];
    __shared__ _Float16 Ws[256 * PADK];
    const int bm = blockIdx.y * 64;
    const int tid = threadIdx.x;
    const int wv = tid >> 6, lane = tid & 63;
    const int l15 = lane & 15, l4 = lane >> 4;
    const int ar = tid >> 2, akq = (tid & 3) * 8;
    const int ga = bm + ar;

    f16x8 ra, rw[4];
    auto loadT = [&](int k0) {
        if (ga < mc) ra = *reinterpret_cast<const f16x8*>(Acat + (size_t)ga * LDC2 + NH + k0 + akq);
        else { f16x8 z = {}; ra = z; }
#pragma unroll
        for (int q = 0; q < 4; ++q)
            rw[q] = *reinterpret_cast<const f16x8*>(Wn16 + (size_t)(ar + 64 * q) * NH + k0 + akq);
    };

    f32x4 acc[16];
#pragma unroll
    for (int c = 0; c < 16; ++c) acc[c] = (f32x4){0.f, 0.f, 0.f, 0.f};

    loadT(0);
    for (int k0 = 0; k0 < NH; k0 += 32) {
        *reinterpret_cast<f16x8*>(&As[ar * PADK + akq]) = ra;
#pragma unroll
        for (int q = 0; q < 4; ++q)
            *reinterpret_cast<f16x8*>(&Ws[(ar + 64 * q) * PADK + akq]) = rw[q];
        __syncthreads();
        if (k0 + 32 < NH) loadT(k0 + 32);
        f16x8 af = *reinterpret_cast<const f16x8*>(&As[(wv * 16 + l15) * PADK + l4 * 8]);
#pragma unroll
        for (int c = 0; c < 16; ++c) {
            f16x8 wf = *reinterpret_cast<const f16x8*>(&Ws[(c * 16 + l15) * PADK + l4 * 8]);
            acc[c] = __builtin_amdgcn_mfma_f32_16x16x32_f16(af, wf, acc[c], 0, 0, 0);
        }
        __syncthreads();
    }

    float pd1[4] = {0.f, 0.f, 0.f, 0.f};
    float pd2[4] = {0.f, 0.f, 0.f, 0.f};
#pragma unroll
    for (int c = 0; c < 16; ++c) {
        int gc = c * 16 + l15;
        float bhn = bhh[512 + gc];
        float usv = us ? us[gc] : 0.f;
        float udv = ud ? ud[gc] : 0.f;
#pragma unroll
        for (int q = 0; q < 4; ++q) {
            int gr = bm + wv * 16 + l4 * 4 + q;
            if (gr >= mc) continue;
            float hn = acc[c][q] + bhn;
            float rr = (float)srz[(size_t)gr * 512 + gc];
            float zz = (float)srz[(size_t)gr * 512 + 256 + gc];
            float inn = (float)innb[(size_t)gr * NH + gc];
            float nn = tanhf(inn + rr * hn);
            size_t xoff = (size_t)gr * LDC2 + NH + gc;
            float xold = (float)Acat[xoff];
            float hv = fmaxf((1.f - zz) * nn + zz * xold, 0.f);
            Acat[xoff] = (_Float16)hv;
            pd1[q] += hv * usv;
            pd2[q] += hv * udv;
        }
    }
    if (us) {
#pragma unroll
        for (int off = 1; off < 16; off <<= 1) {
#pragma unroll
            for (int q = 0; q < 4; ++q) {
                pd1[q] += __shfl_xor(pd1[q], off);
                pd2[q] += __shfl_xor(pd2[q], off);
            }
        }
        if (l15 == 0) {
#pragma unroll
            for (int q = 0; q < 4; ++q) {
                int gr = bm + wv * 16 + l4 * 4 + q;
                if (gr < mc) {
                    dotr[gr] = pd1[q];
                    if (ud) adst[gr] = pd2[q];
                }
            }
        }
    }
}

// ---------------- legacy f32-W MFMA GEMM (mol phase only) ----------------
template<int ACT, int OB, int AF16>
static __device__ __forceinline__ void gemm_core(
    _Float16* As, _Float16* Ws,
    const void* __restrict__ Av, const float* __restrict__ W,
    const float* __restrict__ bias, void* __restrict__ Cout,
    int M, int K, int Nout, int ldA, int ldW, int ldC, int ocol, int Kw, int bn)
{
    const int bm = blockIdx.y * 64;
    const int tid = threadIdx.x;
    const int wv = tid >> 6, lane = tid & 63;
    const int l15 = lane & 15, l4 = lane >> 4;
    const bool kvec = ((K & 31) == 0) && ((ldA & 3) == 0);
    const bool wvec = ((K & 31) == 0) && ((ldW & 3) == 0) && (Kw == K);
    const int ar = tid >> 2, akq = (tid & 3) * 8;

    f32x4 acc[16];
#pragma unroll
    for (int c = 0; c < 16; ++c) acc[c] = (f32x4){0.f, 0.f, 0.f, 0.f};

    for (int k0 = 0; k0 < K; k0 += 32) {
        {
            const int ga = bm + ar;
            _Float16* dstA = &As[ar * PADK + akq];
            if (AF16) {
                const _Float16* A = (const _Float16*)Av;
                if (ga < M) {
                    *reinterpret_cast<f16x8*>(dstA) =
                        *reinterpret_cast<const f16x8*>(A + (size_t)ga * ldA + k0 + akq);
                } else {
#pragma unroll
                    for (int j = 0; j < 8; ++j) dstA[j] = (_Float16)0.f;
                }
            } else {
                const float* A = (const float*)Av;
                if (ga < M && kvec) {
                    const float4* ap4 = reinterpret_cast<const float4*>(A + (size_t)ga * ldA + k0 + akq);
                    float4 v0 = ap4[0], v1 = ap4[1];
                    dstA[0] = (_Float16)v0.x; dstA[1] = (_Float16)v0.y;
                    dstA[2] = (_Float16)v0.z; dstA[3] = (_Float16)v0.w;
                    dstA[4] = (_Float16)v1.x; dstA[5] = (_Float16)v1.y;
                    dstA[6] = (_Float16)v1.z; dstA[7] = (_Float16)v1.w;
                } else {
                    const float* ap = A + (size_t)ga * ldA + k0 + akq;
#pragma unroll
                    for (int j = 0; j < 8; ++j) {
                        int gk = k0 + akq + j;
                        float v = (ga < M && gk < K) ? ap[j] : 0.f;
                        dstA[j] = (_Float16)v;
                    }
                }
            }
        }
#pragma unroll
        for (int q = 0; q < 4; ++q) {
            const int r = ar + 64 * q;
            const int gw = bn + r;
            _Float16* dstW = &Ws[r * PADK + akq];
            if (gw < Nout && wvec) {
                const float4* wp4 = reinterpret_cast<const float4*>(W + (size_t)gw * ldW + k0 + akq);
                float4 v0 = wp4[0], v1 = wp4[1];
                dstW[0] = (_Float16)v0.x; dstW[1] = (_Float16)v0.y;
                dstW[2] = (_Float16)v0.z; dstW[3] = (_Float16)v0.w;
                dstW[4] = (_Float16)v1.x; dstW[5] = (_Float16)v1.y;
                dstW[6] = (_Float16)v1.z; dstW[7] = (_Float16)v1.w;
            } else {
                const float* wp = W + (size_t)gw * ldW + k0 + akq;
#pragma unroll
                for (int j = 0; j < 8; ++j) {
                    int gk = k0 + akq + j;
                    float v = (gw < Nout && gk < Kw) ? wp[j] : 0.f;
                    dstW[j] = (_Float16)v;
                }
            }
        }
        __syncthreads();
        f16x8 af = *reinterpret_cast<const f16x8*>(&As[(wv * 16 + l15) * PADK + l4 * 8]);
#pragma unroll
        for (int c = 0; c < 16; ++c) {
            f16x8 wf = *reinterpret_cast<const f16x8*>(&Ws[(c * 16 + l15) * PADK + l4 * 8]);
            acc[c] = __builtin_amdgcn_mfma_f32_16x16x32_f16(af, wf, acc[c], 0, 0, 0);
        }
        __syncthreads();
    }

#pragma unroll
    for (int c = 0; c < 16; ++c) {
        int gc = bn + c * 16 + l15;
        if (gc >= Nout) continue;
        float bv = bias ? bias[gc] : 0.f;
#pragma unroll
        for (int q = 0; q < 4; ++q) {
            int gr = bm + wv * 16 + l4 * 4 + q;
            if (gr >= M) continue;
            float v = acc[c][q] + bv;
            if (ACT == 1) v = lrelu_f(v);
            else if (ACT == 2) v = (v > 0.f ? v : expm1f(v));
            size_t off = (size_t)gr * ldC + ocol + gc;
            if (OB) ((_Float16*)Cout)[off] = (_Float16)v;
            else    ((float*)Cout)[off] = v;
        }
    }
}

template<int ACT, int OB, int AF16>
__global__ __launch_bounds__(256, 4) void gemm_mfma(
    const void* __restrict__ A, const float* __restrict__ W,
    const float* __restrict__ bias, void* __restrict__ Cout,
    int M, int K, int Nout, int ldA, int ldW, int ldC, int ocol, int Kw)
{
    __shared__ _Float16 As[64 * PADK];
    __shared__ _Float16 Ws[256 * PADK];
    gemm_core<ACT, OB, AF16>(As, Ws, A, W, bias, Cout, M, K, Nout, ldA, ldW, ldC, ocol, Kw,
                             blockIdx.x * 256);
}

template<int ACT, int OB>
__global__ __launch_bounds__(256, 4) void gemm_mfma2(
    const float* __restrict__ A0, const float* __restrict__ A1,
    const float* __restrict__ W0, const float* __restrict__ W1,
    void* __restrict__ C0, void* __restrict__ C1, int M, int K, int Nout)
{
    __shared__ _Float16 As[64 * PADK];
    __shared__ _Float16 Ws[256 * PADK];
    int bn = blockIdx.x * 256;
    if (blockIdx.z == 0)
        gemm_core<ACT, OB, 0>(As, Ws, A0, W0, nullptr, C0, M, K, Nout, K, K, Nout, 0, K, bn);
    else
        gemm_core<ACT, OB, 0>(As, Ws, A1, W1, nullptr, C1, M, K, Nout, K, K, Nout, 0, K, bn);
}

// ---------------- weight conversion (one-time) ----------------
__global__ void cast_w16(const float* __restrict__ src, _Float16* __restrict__ dst,
                         int rows, int cols, int ldsrc, int kout)
{
    int i = blockIdx.x * 256 + threadIdx.x;
    if (i >= rows * kout) return;
    int r = i / kout, k = i % kout;
    dst[i] = (k < cols) ? (_Float16)src[(size_t)r * ldsrc + k] : (_Float16)0.f;
}
__global__ void build_wcat16(const float* __restrict__ wih, const float* __restrict__ whh,
                             _Float16* __restrict__ dst)
{
    int i = blockIdx.x * 256 + threadIdx.x;
    if (i >= 512 * 512) return;
    int j = i >> 9, k = i & 511;
    dst[i] = (_Float16)((k < 256) ? wih[j * 256 + k] : whh[j * 256 + (k - 256)]);
}

__global__ void pad_cast_f16(const float* __restrict__ in, _Float16* __restrict__ out,
                             int M, int Kin, int Kout)
{
    size_t i = (size_t)blockIdx.x * 256 + threadIdx.x;
    if (i >= (size_t)M * Kout) return;
    int r = (int)(i / Kout), k = (int)(i % Kout);
    out[i] = (k < Kin) ? (_Float16)in[(size_t)r * Kin + k] : (_Float16)0.f;
}

// ---------------- fp32 fallback GEMM (final 12-col fc only) ----------------
__global__ __launch_bounds__(256) void gemm_nt(
    const float* __restrict__ A, const float* __restrict__ W,
    const float* __restrict__ bias, float* __restrict__ C,
    int M, int K, int Nout, int ldW, int act)
{
    __shared__ float As[16][65];
    __shared__ float Ws[16][65];
    const int bm = blockIdx.y * 64;
    const int bn = blockIdx.x * 64;
    const int tid = threadIdx.x;
    const int tr = tid >> 4, tc = tid & 15;
    const int lrow = tid >> 2, lk = (tid & 3) * 4;
    float acc[4][4] = {};
    for (int k0 = 0; k0 < K; k0 += 16) {
#pragma unroll
        for (int j = 0; j < 4; ++j) {
            int gk = k0 + lk + j;
            int ga = bm + lrow;
            As[lk + j][lrow] = (ga < M && gk < K) ? A[(size_t)ga * K + gk] : 0.f;
            int gw = bn + lrow;
            Ws[lk + j][lrow] = (gw < Nout && gk < K) ? W[(size_t)gw * ldW + gk] : 0.f;
        }
        __syncthreads();
#pragma unroll
        for (int kk = 0; kk < 16; ++kk) {
            float av[4], bv[4];
#pragma unroll
            for (int i = 0; i < 4; ++i) av[i] = As[kk][tr * 4 + i];
#pragma unroll
            for (int i = 0; i < 4; ++i) bv[i] = Ws[kk][tc * 4 + i];
#pragma unroll
            for (int i = 0; i < 4; ++i)
#pragma unroll
                for (int j = 0; j < 4; ++j) acc[i][j] += av[i] * bv[j];
        }
        __syncthreads();
    }
#pragma unroll
    for (int i = 0; i < 4; ++i) {
        int m = bm + tr * 4 + i;
        if (m >= M) continue;
#pragma unroll
        for (int j = 0; j < 4; ++j) {
            int n = bn + tc * 4 + j;
            if (n >= Nout) continue;
            float v = acc[i][j];
            if (bias) v += bias[n];
            if (act == 1) v = lrelu_f(v);
            C[(size_t)m * Nout + n] = v;
        }
    }
}

// ---------------- CSR/CSC build ----------------
__global__ void zero_i32(int* p, int n) {
    int i = blockIdx.x * 256 + threadIdx.x;
    if (i < n) p[i] = 0;
}
__global__ void hist_k(const int* __restrict__ key, int* __restrict__ deg, int E) {
    int i = blockIdx.x * 256 + threadIdx.x;
    if (i < E) atomicAdd(&deg[key[i]], 1);
}
__global__ __launch_bounds__(256) void scan_pass1(
    const int* __restrict__ deg, int* __restrict__ bsum, int Nn)
{
    __shared__ int lds[256];
    int b = blockIdx.x, t = threadIdx.x;
    int base = b * SCAN_TILE + t * 8;
    int s = 0;
#pragma unroll
    for (int q = 0; q < 8; ++q) { int i = base + q; if (i < Nn) s += deg[i]; }
    lds[t] = s;
    __syncthreads();
    for (int off = 128; off; off >>= 1) {
        if (t < off) lds[t] += lds[t + off];
        __syncthreads();
    }
    if (t == 0) bsum[b] = lds[0];
}
__global__ __launch_bounds__(256) void scan_pass2(
    const int* __restrict__ bsum, int* __restrict__ boff, int nb, int* __restrict__ total)
{
    __shared__ int lds[256];
    int t = threadIdx.x;
    int v = (t < nb) ? bsum[t] : 0;
    lds[t] = v;
    __syncthreads();
    for (int off = 1; off < 256; off <<= 1) {
        int u = (t >= off) ? lds[t - off] : 0;
        __syncthreads();
        lds[t] += u;
        __syncthreads();
    }
    if (t < nb) boff[t] = lds[t] - v;
    if (t == 255 && total) *total = lds[255];
}
__global__ __launch_bounds__(256) void scan_pass3(
    const int* __restrict__ deg, const int* __restrict__ boff,
    int* __restrict__ rowptr, int* __restrict__ cursor, int Nn)
{
    __shared__ int lds[256];
    int b = blockIdx.x, t = threadIdx.x;
    int base = b * SCAN_TILE + t * 8;
    int v[8];
    int s = 0;
#pragma unroll
    for (int q = 0; q < 8; ++q) { int i = base + q; v[q] = (i < Nn) ? deg[i] : 0; s += v[q]; }
    lds[t] = s;
    __syncthreads();
    for (int off = 1; off < 256; off <<= 1) {
        int u = (t >= off) ? lds[t - off] : 0;
        __syncthreads();
        lds[t] += u;
        __syncthreads();
    }
    int run = boff[b] + lds[t] - s;
#pragma unroll
    for (int q = 0; q < 8; ++q) {
        int i = base + q;
        if (i < Nn) { rowptr[i] = run; cursor[i] = run; run += v[q]; }
    }
}
__global__ void csr_scatter(const int* __restrict__ src, const int* __restrict__ dst,
                            int* __restrict__ cursor, int* __restrict__ esrc,
                            int* __restrict__ pos, int E)
{
    int e = blockIdx.x * 256 + threadIdx.x;
    if (e < E) {
        int p = atomicAdd(&cursor[dst[e]], 1);
        esrc[p] = src[e];
        pos[e] = p;
    }
}
__global__ void csc_scatter(const int* __restrict__ src, int* __restrict__ cursor,
                            int* __restrict__ seid, int E)
{
    int e = blockIdx.x * 256 + threadIdx.x;
    if (e < E) {
        int p = atomicAdd(&cursor[src[e]], 1);
        seid[p] = e;
    }
}
__global__ void edge_csc_build(const float* __restrict__ edge_attr, const int* __restrict__ seid,
                               const int* __restrict__ pos, _Float16* __restrict__ ecsc,
                               int* __restrict__ pcsc, int E)
{
    int p = blockIdx.x * 256 + threadIdx.x;
    if (p >= E) return;
    int e = seid[p];
    pcsc[p] = pos[e];
    const float* ep = edge_attr + (size_t)e * FEDGE;
#pragma unroll
    for (int f = 0; f < FEDGE; ++f) ecsc[(size_t)p * 8 + f] = (_Float16)ep[f];
    ecsc[(size_t)p * 8 + 7] = (_Float16)0.f;
}
__global__ void gptr_build(const int* __restrict__ batch, int* __restrict__ gptr, int Nn, int G) {
    int g = blockIdx.x * 256 + threadIdx.x;
    if (g > G) return;
    int lo = 0, hi = Nn;
    while (lo < hi) { int mid = (lo + hi) >> 1; if (batch[mid] < g) lo = mid + 1; else hi = mid; }
    gptr[g] = lo;
}

// ---------------- GATE src-side partial logit (CSC, packed f16, 4-edge ILP) ----------------
__global__ __launch_bounds__(256) void gate_part_csc(
    const _Float16* __restrict__ nodepart, const _Float16* __restrict__ ecsc,
    const float* __restrict__ gate_lin1_w, const float* __restrict__ att_l,
    const int* __restrict__ srowptr, const int* __restrict__ pcsc,
    float* __restrict__ elogp, int Nn)
{
    int wv = threadIdx.x >> 6, lane = threadIdx.x & 63;
    int h0 = lane * 4;
    f16x2 wr2[2][FEDGE], al2[2];
#pragma unroll
    for (int p = 0; p < 2; ++p) {
        int ha = h0 + 2 * p, hb = ha + 1;
#pragma unroll
        for (int f = 0; f < FEDGE; ++f) {
            wr2[p][f][0] = (_Float16)gate_lin1_w[(size_t)ha * LDW_GATE1 + NH + f];
            wr2[p][f][1] = (_Float16)gate_lin1_w[(size_t)hb * LDW_GATE1 + NH + f];
        }
        al2[p][0] = (_Float16)att_l[ha];
        al2[p][1] = (_Float16)att_l[hb];
    }
    for (int s = blockIdx.x * 4 + wv; s < Nn; s += gridDim.x * 4) {
        int beg = srowptr[s], end = srowptr[s + 1];
        if (beg >= end) continue;
        f16x4 np4 = *reinterpret_cast<const f16x4*>(nodepart + (size_t)s * NH + h0);
        f16x2 np2[2];
        np2[0][0] = np4[0]; np2[0][1] = np4[1];
        np2[1][0] = np4[2]; np2[1][1] = np4[3];
        for (int j0 = beg; j0 < end; j0 += 4) {
            int nb = end - j0; if (nb > 4) nb = 4;
            f16x8 ev[4];
            int pp[4];
#pragma unroll
            for (int k = 0; k < 4; ++k) {
                int j = (k < nb) ? j0 + k : beg;
                pp[k] = pcsc[j];
                ev[k] = *reinterpret_cast<const f16x8*>(ecsc + (size_t)j * 8);
            }
            float acc[4];
#pragma unroll
            for (int k = 0; k < 4; ++k) {
                f16x2 v0 = np2[0], v1 = np2[1];
#pragma unroll
                for (int f = 0; f < FEDGE; ++f) {
                    f16x2 e2; e2[0] = ev[k][f]; e2[1] = ev[k][f];
                    v0 += e2 * wr2[0][f];
                    v1 += e2 * wr2[1][f];
                }
                float a = __builtin_amdgcn_fdot2(lrelu2(v0), al2[0], 0.f, false);
                a = __builtin_amdgcn_fdot2(lrelu2(v1), al2[1], a, false);
                acc[k] = a;
            }
#pragma unroll
            for (int off = 32; off; off >>= 1) {
#pragma unroll
                for (int k = 0; k < 4; ++k) acc[k] += __shfl_xor(acc[k], off);
            }
            if (lane == 0) {
#pragma unroll
                for (int k = 0; k < 4; ++k) if (k < nb) elogp[pp[k]] = acc[k];
            }
        }
    }
}

// ---------------- fused attention aggregation (CSR, wave per dst, LDS alpha cache) ----------------
__global__ __launch_bounds__(256) void gat_agg_csr(
    const _Float16* __restrict__ X, int ldX,
    const float* __restrict__ asrc, const float* __restrict__ adst,
    const int* __restrict__ rowptr, const int* __restrict__ esrc,
    _Float16* __restrict__ hout, int Nn)
{
    __shared__ float salpha[4][64];
    int wv = threadIdx.x >> 6, lane = threadIdx.x & 63;
    int d = blockIdx.x * 4 + wv;
    if (d >= Nn) return;
    int beg = rowptr[d], end = rowptr[d + 1];
    float a0 = 0.f, a1 = 0.f, a2 = 0.f, a3 = 0.f, ssum = 0.f;
    if (beg < end) {
        float ad = adst[d];
        float m = -3.4e38f;
        for (int j = beg + lane; j < end; j += 64)
            m = fmaxf(m, lrelu_f(asrc[esrc[j]] + ad));
#pragma unroll
        for (int off = 32; off; off >>= 1) m = fmaxf(m, __shfl_xor(m, off));
        for (int c0 = beg; c0 < end; c0 += 64) {
            int j = c0 + lane;
            float e = (j < end) ? expf(lrelu_f(asrc[esrc[j]] + ad) - m) : 0.f;
            salpha[wv][lane] = e;
            ssum += e;
            int cend = end - c0; if (cend > 64) cend = 64;
            for (int k = 0; k < cend; ++k) {
                float alk = salpha[wv][k];
                int sj = esrc[c0 + k];
                f16x4 xv = *reinterpret_cast<const f16x4*>(X + (size_t)sj * ldX + lane * 4);
                a0 += alk * (float)xv[0]; a1 += alk * (float)xv[1];
                a2 += alk * (float)xv[2]; a3 += alk * (float)xv[3];
            }
        }
#pragma unroll
        for (int off = 32; off; off >>= 1) ssum += __shfl_xor(ssum, off);
        float inv = 1.f / (ssum + 1e-16f);
        a0 *= inv; a1 *= inv; a2 *= inv; a3 *= inv;
    }
    f16x4 o;
    o[0] = (_Float16)a0; o[1] = (_Float16)a1; o[2] = (_Float16)a2; o[3] = (_Float16)a3;
    *reinterpret_cast<f16x4*>(hout + (size_t)d * NH + lane * 4) = o;
}

__global__ __launch_bounds__(256) void gate_agg_csr(
    const _Float16* __restrict__ X, int ldX,
    const float* __restrict__ elogp, const float* __restrict__ dotr,
    const int* __restrict__ rowptr, const int* __restrict__ esrc,
    _Float16* __restrict__ hout, int Nn)
{
    __shared__ float salpha[4][64];
    int wv = threadIdx.x >> 6, lane = threadIdx.x & 63;
    int d = blockIdx.x * 4 + wv;
    if (d >= Nn) return;
    int beg = rowptr[d], end = rowptr[d + 1];
    float a0 = 0.f, a1 = 0.f, a2 = 0.f, a3 = 0.f, ssum = 0.f;
    if (beg < end) {
        float dd = dotr[d];
        float m = -3.4e38f;
        for (int j = beg + lane; j < end; j += 64)
            m = fmaxf(m, lrelu_f(elogp[j] + dd));
#pragma unroll
        for (int off = 32; off; off >>= 1) m = fmaxf(m, __shfl_xor(m, off));
        for (int c0 = beg; c0 < end; c0 += 64) {
            int j = c0 + lane;
            float e = (j < end) ? expf(lrelu_f(elogp[j] + dd) - m) : 0.f;
            salpha[wv][lane] = e;
            ssum += e;
            int cend = end - c0; if (cend > 64) cend = 64;
            for (int k = 0; k < cend; ++k) {
                float alk = salpha[wv][k];
                int sj = esrc[c0 + k];
                f16x4 xv = *reinterpret_cast<const f16x4*>(X + (size_t)sj * ldX + lane * 4);
                a0 += alk * (float)xv[0]; a1 += alk * (float)xv[1];
                a2 += alk * (float)xv[2]; a3 += alk * (float)xv[3];
            }
        }
#pragma unroll
        for (int off = 32; off; off >>= 1) ssum += __shfl_xor(ssum, off);
        float inv = 1.f / (ssum + 1e-16f);
        a0 *= inv; a1 *= inv; a2 *= inv; a3 *= inv;
    }
    f16x4 o;
    o[0] = (_Float16)a0; o[1] = (_Float16)a1; o[2] = (_Float16)a2; o[3] = (_Float16)a3;
    *reinterpret_cast<f16x4*>(hout + (size_t)d * NH + lane * 4) = o;
}

__global__ __launch_bounds__(256) void mol_agg_csr(
    const _Float16* __restrict__ X, int ldX,
    const float* __restrict__ dotr, const float* __restrict__ ddot,
    const int* __restrict__ gptr, float* __restrict__ hout, int G)
{
    __shared__ float salpha[4][64];
    int wv = threadIdx.x >> 6, lane = threadIdx.x & 63;
    int g = blockIdx.x * 4 + wv;
    if (g >= G) return;
    int beg = gptr[g], end = gptr[g + 1];
    float a0 = 0.f, a1 = 0.f, a2 = 0.f, a3 = 0.f, ssum = 0.f;
    if (beg < end) {
        float dg = ddot[g];
        float m = -3.4e38f;
        for (int i = beg + lane; i < end; i += 64)
            m = fmaxf(m, lrelu_f(dotr[i] + dg));
#pragma unroll
        for (int off = 32; off; off >>= 1) m = fmaxf(m, __shfl_xor(m, off));
        for (int c0 = beg; c0 < end; c0 += 64) {
            int i = c0 + lane;
            float e = (i < end) ? expf(lrelu_f(dotr[i] + dg) - m) : 0.f;
            salpha[wv][lane] = e;
            ssum += e;
            int cend = end - c0; if (cend > 64) cend = 64;
            for (int k = 0; k < cend; ++k) {
                float alk = salpha[wv][k];
                f16x4 xv = *reinterpret_cast<const f16x4*>(X + (size_t)(c0 + k) * ldX + lane * 4);
                a0 += alk * (float)xv[0]; a1 += alk * (float)xv[1];
                a2 += alk * (float)xv[2]; a3 += alk * (float)xv[3];
            }
        }
#pragma unroll
        for (int off = 32; off; off >>= 1) ssum += __shfl_xor(ssum, off);
        float inv = 1.f / (ssum + 1e-16f);
        a0 *= inv; a1 *= inv; a2 *= inv; a3 *= inv;
    }
    float* hr = hout + (size_t)g * NH + lane * 4;
    hr[0] = a0; hr[1] = a1; hr[2] = a2; hr[3] = a3;
}

__global__ __launch_bounds__(256) void graph_sum_relu(
    const _Float16* __restrict__ X, int ldX, const int* __restrict__ gptr,
    float* __restrict__ out, int G)
{
    int wv = threadIdx.x >> 6, lane = threadIdx.x & 63;
    int g = blockIdx.x * 4 + wv;
    if (g >= G) return;
    int beg = gptr[g], end = gptr[g + 1];
    float a0 = 0.f, a1 = 0.f, a2 = 0.f, a3 = 0.f;
    for (int i = beg; i < end; ++i) {
        f16x4 xv = *reinterpret_cast<const f16x4*>(X + (size_t)i * ldX + lane * 4);
        a0 += (float)xv[0]; a1 += (float)xv[1]; a2 += (float)xv[2]; a3 += (float)xv[3];
    }
    float* hr = out + (size_t)g * NH + lane * 4;
    hr[0] = fmaxf(a0, 0.f); hr[1] = fmaxf(a1, 0.f);
    hr[2] = fmaxf(a2, 0.f); hr[3] = fmaxf(a3, 0.f);
}

template<typename TX>
__global__ __launch_bounds__(256) void node_dot(
    const TX* __restrict__ X, int ldX, const float* __restrict__ v1, const float* __restrict__ v2,
    float* __restrict__ o1, float* __restrict__ o2, int M)
{
    __shared__ float s1[NH], s2[NH];
    int tid = threadIdx.x;
    s1[tid] = v1[tid];
    s2[tid] = v2 ? v2[tid] : 0.f;
    __syncthreads();
    int wv = tid >> 6, lane = tid & 63;
    for (int n = blockIdx.x * 4 + wv; n < M; n += gridDim.x * 4) {
        float a1 = 0.f, a2 = 0.f;
#pragma unroll
        for (int i = 0; i < 4; ++i) {
            int hh = i * 64 + lane;
            float xv = (float)X[(size_t)n * ldX + hh];
            a1 += xv * s1[hh];
            a2 += xv * s2[hh];
        }
#pragma unroll
        for (int off = 32; off; off >>= 1) { a1 += __shfl_xor(a1, off); a2 += __shfl_xor(a2, off); }
        if (lane == 0) { o1[n] = a1; if (o2) o2[n] = a2; }
    }
}

__global__ __launch_bounds__(256) void matvec_left(
    const float* __restrict__ Wm, const float* __restrict__ a, float* __restrict__ v)
{
    int j = threadIdx.x;
    float s = 0.f;
    for (int i = 0; i < NH; ++i) s += a[i] * Wm[(size_t)i * NH + j];
    v[j] = s;
}

// mol GRU combine (f32 hprev/out), gi/gh f16 dense NH3
__global__ __launch_bounds__(256) void gru_combine(
    const _Float16* __restrict__ gi, const _Float16* __restrict__ gh,
    const float* __restrict__ b_ih, const float* __restrict__ b_hh,
    const float* __restrict__ hprev, float* __restrict__ out, int M)
{
    size_t t = (size_t)blockIdx.x * 256 + threadIdx.x;
    if (t >= (size_t)M * 32) return;
    int n = (int)(t >> 5), j0 = ((int)t & 31) * 8;
    size_t b3 = (size_t)n * NH3;
    f16x8 vir = *reinterpret_cast<const f16x8*>(&gi[b3 + j0]);
    f16x8 viz = *reinterpret_cast<const f16x8*>(&gi[b3 + NH + j0]);
    f16x8 vin = *reinterpret_cast<const f16x8*>(&gi[b3 + 2 * NH + j0]);
    f16x8 vhr = *reinterpret_cast<const f16x8*>(&gh[b3 + j0]);
    f16x8 vhz = *reinterpret_cast<const f16x8*>(&gh[b3 + NH + j0]);
    f16x8 vhn = *reinterpret_cast<const f16x8*>(&gh[b3 + 2 * NH + j0]);
    size_t hb = (size_t)n * NH + j0;
#pragma unroll
    for (int q = 0; q < 8; ++q) {
        int j = j0 + q;
        float r = 1.f / (1.f + expf(-((float)vir[q] + b_ih[j] + (float)vhr[q] + b_hh[j])));
        float z = 1.f / (1.f + expf(-((float)viz[q] + b_ih[NH + j] + (float)vhz[q] + b_hh[NH + j])));
        float nn = tanhf((float)vin[q] + b_ih[2 * NH + j] + r * ((float)vhn[q] + b_hh[2 * NH + j]));
        out[hb + q] = fmaxf((1.f - z) * nn + z * hprev[hb + q], 0.f);
    }
}

extern "C" void kernel_launch(void* const* d_in, const int* in_sizes, int n_in,
                              void* d_out, int out_size, void* d_ws, size_t ws_size,
                              hipStream_t stream)
{
    const float* x          = (const float*)d_in[0];
    const float* edge_attr  = (const float*)d_in[1];
    const float* lin1_w     = (const float*)d_in[2];
    const float* lin1_b     = (const float*)d_in[3];
    const float* gate_att_l = (const float*)d_in[4];
    const float* gate_att_r = (const float*)d_in[5];
    const float* gate_lin1_w= (const float*)d_in[6];
    const float* gate_lin2_w= (const float*)d_in[7];
    const float* gate_bias  = (const float*)d_in[8];
    const float* atom_lin_w = (const float*)d_in[9];
    const float* atom_att_src=(const float*)d_in[10];
    const float* atom_att_dst=(const float*)d_in[11];
    const float* atom_bias  = (const float*)d_in[12];
    const float* gru_w_ih   = (const float*)d_in[13];
    const float* gru_w_hh   = (const float*)d_in[14];
    const float* gru_b_ih   = (const float*)d_in[15];
    const float* gru_b_hh   = (const float*)d_in[16];
    const float* mol_lin_w  = (const float*)d_in[17];
    const float* mol_att_src= (const float*)d_in[18];
    const float* mol_att_dst= (const float*)d_in[19];
    const float* mol_bias   = (const float*)d_in[20];
    const float* mol_gru_w_ih=(const float*)d_in[21];
    const float* mol_gru_w_hh=(const float*)d_in[22];
    const float* mol_gru_b_ih=(const float*)d_in[23];
    const float* mol_gru_b_hh=(const float*)d_in[24];
    const float* lin2_w     = (const float*)d_in[25];
    const float* lin2_b     = (const float*)d_in[26];
    const float* fc_w       = (const float*)d_in[27];
    const float* fc_b       = (const float*)d_in[28];
    const int*   edge_index = (const int*)d_in[29];
    const int*   batch      = (const int*)d_in[30];

    const int N = in_sizes[0] / FNODE;
    const int E = in_sizes[1] / FEDGE;
    const int G = NGRAPH;
    const int* src = edge_index;
    const int* dst = edge_index + E;

    float* w = (float*)d_ws;
    size_t o = 0;
    auto alloc = [&](size_t cnt) { size_t r = o; o += cnt; return r; };
    const size_t o_B1cat = alloc((size_t)N * NH);          // f16 N x 512: [tmp | xcur]
    const size_t o_B2    = alloc((size_t)N * NH / 2);      // f16 nodepart -> hraw ; mol f32 bufs
    const size_t o_B3    = alloc((size_t)CHUNK * 384);     // inn(256)+srz(512) f16 ; xpad
    const size_t o_w16   = alloc((size_t)972000);          // f16 weight pool
    const size_t o_elog  = alloc((size_t)E);
    const size_t o_dotr  = alloc((size_t)N);
    const size_t o_adst  = alloc((size_t)N);
    const size_t o_ddot  = alloc((size_t)G);
    const size_t o_vvec  = alloc((size_t)NH);
    const size_t o_usrc  = alloc((size_t)NH);
    const size_t o_udst  = alloc((size_t)NH);
    const size_t o_rowp  = alloc((size_t)N + 1);
    const size_t o_srowp = alloc((size_t)N + 1);
    const size_t o_deg   = alloc((size_t)N);
    const size_t o_curs  = alloc((size_t)N);
    const size_t o_bsum  = alloc((size_t)512);
    const size_t o_esrc  = alloc((size_t)E);
    const size_t o_pos   = alloc((size_t)E);
    const size_t o_seid  = alloc((size_t)E);
    const size_t o_ecsc  = alloc((size_t)E * 4);
    const size_t o_pcsc  = alloc((size_t)E);
    const size_t o_gptr  = alloc((size_t)G + 1);
    if (o * sizeof(float) > ws_size) {
        fprintf(stderr, "kernel_launch: ws too small: need %zu have %zu\n", o * 4, ws_size);
        return;
    }

    _Float16* B1cat = (_Float16*)(w + o_B1cat);
    _Float16* xcur  = B1cat + NH;
    _Float16* B2 = (_Float16*)(w + o_B2);
    float* B3   = w + o_B3;
    _Float16* w16 = (_Float16*)(w + o_w16);
    _Float16* lin116   = w16;                       // 256*160
    _Float16* gate1a16 = lin116 + 40960;            // 256*256
    _Float16* gate216  = gate1a16 + 65536;          // 256*256
    _Float16* atom16   = gate216 + 65536;           // 3 * 65536
    _Float16* wihn16   = atom16 + 3 * 65536;        // 4 * 65536
    _Float16* whhn16   = wihn16 + 4 * 65536;        // 4 * 65536
    _Float16* wcat16   = whhn16 + 4 * 65536;        // 4 * 262144
    float* elog = w + o_elog;
    float* dotr = w + o_dotr;
    float* adst = w + o_adst;
    float* ddot = w + o_ddot;
    float* vvec = w + o_vvec;
    float* usrc = w + o_usrc;
    float* udst = w + o_udst;
    int* rowptr  = (int*)(w + o_rowp);
    int* srowptr = (int*)(w + o_srowp);
    int* deg     = (int*)(w + o_deg);
    int* cursor  = (int*)(w + o_curs);
    int* bsum    = (int*)(w + o_bsum);
    int* boff    = bsum + 256;
    int* esrc    = (int*)(w + o_esrc);
    int* pos     = (int*)(w + o_pos);
    int* seid    = (int*)(w + o_seid);
    _Float16* ecsc = (_Float16*)(w + o_ecsc);
    int* pcsc    = (int*)(w + o_pcsc);
    int* gptr    = (int*)(w + o_gptr);

    // mol-phase f32 sub-buffers inside B2
    float* B2f = (float*)B2;
    float*    gout   = B2f;
    float*    hraw_g = B2f + (size_t)G * NH;
    float*    h_g    = B2f + (size_t)2 * G * NH;
    _Float16* gig    = (_Float16*)(B2f + (size_t)3 * G * NH);
    _Float16* ghg    = (_Float16*)(B2f + (size_t)3 * G * NH + (size_t)G * NH3 / 2);
    float*    emb    = B2f + (size_t)3 * G * NH + (size_t)G * NH3;

    const int BLK = 256;
    auto cdiv = [](size_t a, size_t b) { return (int)((a + b - 1) / b); };
    const int gridNodeWave = cdiv(N, 4);
    const int gridEdgeThr = cdiv(E, BLK);
    const int gridNodeThr = cdiv(N, BLK);
    const int CAP = 4096;
    const int gridNodeCap = gridNodeWave < CAP ? gridNodeWave : CAP;
    const int nScanB = cdiv(N, SCAN_TILE);

    auto run_scan = [&](int* rowp) {
        scan_pass1<<<nScanB, BLK, 0, stream>>>(deg, bsum, N);
        scan_pass2<<<1, BLK, 0, stream>>>(bsum, boff, nScanB, rowp + N);
        scan_pass3<<<nScanB, BLK, 0, stream>>>(deg, boff, rowp, cursor, N);
    };

    // ---------- weight conversion (one-time) ----------
    cast_w16<<<cdiv(256 * 160, BLK), BLK, 0, stream>>>(lin1_w, lin116, 256, FNODE, FNODE, 160);
    cast_w16<<<cdiv(65536, BLK), BLK, 0, stream>>>(gate_lin1_w, gate1a16, 256, 256, LDW_GATE1, 256);
    cast_w16<<<cdiv(65536, BLK), BLK, 0, stream>>>(gate_lin2_w, gate216, 256, 256, 256, 256);
    for (int l = 0; l < 3; ++l)
        cast_w16<<<cdiv(65536, BLK), BLK, 0, stream>>>(atom_lin_w + (size_t)l * 65536,
                                                       atom16 + (size_t)l * 65536, 256, 256, 256, 256);
    for (int l = 0; l < 4; ++l) {
        const float* wih = gru_w_ih + (size_t)l * NH3 * NH;
        const float* whh = gru_w_hh + (size_t)l * NH3 * NH;
        build_wcat16<<<1024, BLK, 0, stream>>>(wih, whh, wcat16 + (size_t)l * 262144);
        cast_w16<<<cdiv(65536, BLK), BLK, 0, stream>>>(wih + 512 * NH, wihn16 + (size_t)l * 65536,
                                                       256, 256, 256, 256);
        cast_w16<<<cdiv(65536, BLK), BLK, 0, stream>>>(whh + 512 * NH, whhn16 + (size_t)l * 65536,
                                                       256, 256, 256, 256);
    }

    // ---------- CSR + CSC build (once) ----------
    zero_i32<<<gridNodeThr, BLK, 0, stream>>>(deg, N);
    hist_k<<<gridEdgeThr, BLK, 0, stream>>>(dst, deg, E);
    run_scan(rowptr);
    csr_scatter<<<gridEdgeThr, BLK, 0, stream>>>(src, dst, cursor, esrc, pos, E);
    zero_i32<<<gridNodeThr, BLK, 0, stream>>>(deg, N);
    hist_k<<<gridEdgeThr, BLK, 0, stream>>>(src, deg, E);
    run_scan(srowptr);
    csc_scatter<<<gridEdgeThr, BLK, 0, stream>>>(src, cursor, seid, E);
    edge_csc_build<<<gridEdgeThr, BLK, 0, stream>>>(edge_attr, seid, pos, ecsc, pcsc, E);
    gptr_build<<<cdiv(G + 1, BLK), BLK, 0, stream>>>(batch, gptr, N, G);

    // Per-layer tail
    auto run_tail = [&](const _Float16* Wh16, const float* bh, int l,
                        const float* bih, const float* bhh,
                        const float* usv, const float* udv) {
        _Float16* innb = (_Float16*)B3;                 // CHUNK*256 f16
        _Float16* srz  = innb + (size_t)CHUNK * NH;     // CHUNK*512 f16
        dim3 gFull(1, cdiv(N, 64));
        gemm16<2><<<gFull, BLK, 0, stream>>>(B2, Wh16, bh, B1cat, N, NH, NH, LDC2, 0);
        for (int c0 = 0; c0 < N; c0 += CHUNK) {
            int mc = (N - c0) < CHUNK ? (N - c0) : CHUNK;
            dim3 gA(1, cdiv(mc, 64), 2);
            gemm_gru_rzi16<<<gA, BLK, 0, stream>>>(B1cat + (size_t)c0 * LDC2,
                                                   wcat16 + (size_t)l * 262144,
                                                   wihn16 + (size_t)l * 65536,
                                                   bih, bhh, srz, innb, mc);
            dim3 gB(1, cdiv(mc, 64));
            gemm_gru_b16<<<gB, BLK, 0, stream>>>(B1cat + (size_t)c0 * LDC2,
                                                 whhn16 + (size_t)l * 65536, bhh,
                                                 srz, innb, usv, udv, dotr + c0, adst + c0, mc);
        }
    };

    dim3 gridNH(1, cdiv(N, 64));

    // ---------- x0 = lrelu(x @ lin1^T + b) -> xcur ----------
    _Float16* xpad = (_Float16*)B3;
    pad_cast_f16<<<cdiv((size_t)N * KPAD_X, BLK), BLK, 0, stream>>>(x, xpad, N, FNODE, KPAD_X);
    gemm16<1><<<gridNH, BLK, 0, stream>>>(xpad, lin116, lin1_b, B1cat, N, KPAD_X, KPAD_X, LDC2, NH);

    // ---------- GATEConv ----------
    gemm16<0><<<gridNH, BLK, 0, stream>>>(xcur, gate1a16, nullptr, B2, N, NH, LDC2, NH, 0);
    node_dot<_Float16><<<gridNodeCap, BLK, 0, stream>>>(xcur, LDC2, gate_att_r, nullptr,
                                                        dotr, nullptr, N);
    gate_part_csc<<<gridNodeCap, BLK, 0, stream>>>(B2, ecsc, gate_lin1_w, gate_att_l,
                                                   srowptr, pcsc, elog, N);
    gate_agg_csr<<<gridNodeWave, BLK, 0, stream>>>(xcur, LDC2, elog, dotr, rowptr, esrc, B2, N);
    matvec_left<<<1, BLK, 0, stream>>>(atom_lin_w, atom_att_src, usrc);
    matvec_left<<<1, BLK, 0, stream>>>(atom_lin_w, atom_att_dst, udst);
    run_tail(gate216, gate_bias, 0, gru_b_ih, gru_b_hh, usrc, udst);

    // ---------- 3 GATConv layers ----------
    for (int l = 0; l < 3; ++l) {
        gat_agg_csr<<<gridNodeWave, BLK, 0, stream>>>(xcur, LDC2, dotr, adst, rowptr, esrc, B2, N);
        const float* nus = usrc;
        const float* nud = udst;
        if (l < 2) {
            matvec_left<<<1, BLK, 0, stream>>>(atom_lin_w + (size_t)(l + 1) * NH * NH,
                                               atom_att_src + (l + 1) * NH, usrc);
            matvec_left<<<1, BLK, 0, stream>>>(atom_lin_w + (size_t)(l + 1) * NH * NH,
                                               atom_att_dst + (l + 1) * NH, udst);
        } else {
            matvec_left<<<1, BLK, 0, stream>>>(mol_lin_w, mol_att_src, usrc);
            nud = nullptr;
        }
        run_tail(atom16 + (size_t)l * 65536, atom_bias + l * NH, l + 1,
                 gru_b_ih + (size_t)(l + 1) * NH3, gru_b_hh + (size_t)(l + 1) * NH3, nus, nud);
    }

    // ---------- Molecule pooling ----------
    const int gridGWave = cdiv(G, 4);
    graph_sum_relu<<<gridGWave, BLK, 0, stream>>>(xcur, LDC2, gptr, gout, G);
    matvec_left<<<1, BLK, 0, stream>>>(mol_lin_w, mol_att_dst, vvec);

    dim3 gridGH(1, cdiv(G, 64));
    dim3 gridGD(3, cdiv(G, 64), 2);
    for (int t = 0; t < 2; ++t) {
        node_dot<float><<<gridGWave, BLK, 0, stream>>>(gout, NH, vvec, nullptr, ddot, nullptr, G);
        mol_agg_csr<<<gridGWave, BLK, 0, stream>>>(xcur, LDC2, dotr, ddot, gptr, hraw_g, G);
        gemm_mfma<2, 0, 0><<<gridGH, BLK, 0, stream>>>(hraw_g, mol_lin_w, mol_bias, h_g,
                                                       G, NH, NH, NH, NH, NH, 0, NH);
        gemm_mfma2<0, 1><<<gridGD, BLK, 0, stream>>>(h_g, gout, mol_gru_w_ih, mol_gru_w_hh,
                                                     gig, ghg, G, NH, NH3);
        gru_combine<<<cdiv((size_t)G * 32, BLK), BLK, 0, stream>>>(
            gig, ghg, mol_gru_b_ih, mol_gru_b_hh, gout, gout, G);
    }

    // ---------- readout ----------
    gemm_mfma<0, 0, 0><<<gridGH, BLK, 0, stream>>>(gout, lin2_w, lin2_b, emb,
                                                   G, NH, NH, NH, NH, NH, 0, NH);
    dim3 gridFc(1, cdiv(G, 64));
    gemm_nt<<<gridFc, BLK, 0, stream>>>(emb, fc_w, fc_b, (float*)d_out, G, NH, NTASK, NH, 0);
}

// Round 16
// 2806.326 us; speedup vs baseline: 1.1875x; 1.1875x over previous
//
#include <hip/hip_runtime.h>
#include <math.h>
#include <stdio.h>
#include <stdint.h>

#define NH 256
#define NH3 768
#define FNODE 133
#define FEDGE 7
#define LDW_GATE1 263   // H + F_EDGE
#define NGRAPH 4096
#define NTASK 12
#define SLOPE 0.01f
#define CHUNK 25000
#define PADK 40         // f16 elems per LDS row: 32 + 8 pad (80B stride, 16B aligned)
#define KPAD_X 160      // x padded K (133 -> 160)
#define LDC2 512        // interleaved node-state row stride (f16): [tmp | xcur]
#define SCAN_TILE 2048

typedef __attribute__((ext_vector_type(4))) float f32x4;
typedef __attribute__((ext_vector_type(8))) _Float16 f16x8;
typedef __attribute__((ext_vector_type(4))) _Float16 f16x4;
typedef __attribute__((ext_vector_type(2))) _Float16 f16x2;

static __device__ __forceinline__ float lrelu_f(float x) { return x > 0.f ? x : SLOPE * x; }
static __device__ __forceinline__ f16x2 lrelu2(f16x2 v) {
    f16x2 z = {(_Float16)0.f, (_Float16)0.f};
    f16x2 s = {(_Float16)SLOPE, (_Float16)SLOPE};
    return __builtin_elementwise_max(v, z) + __builtin_elementwise_min(v, z) * s;
}

// ============ pipelined f16-weight GEMM core (BM=64, BN=256, depth-1 prefetch) ============
template<int ACT>
static __device__ __forceinline__ void gemm16_core(
    _Float16* As, _Float16* Ws,
    const _Float16* __restrict__ A, const _Float16* __restrict__ Wf,
    const float* __restrict__ bias, const float* __restrict__ bias2,
    _Float16* __restrict__ Cout,
    int M, int K, int ldA, int ldC, int ocol)
{
    const int bm = blockIdx.y * 64;
    const int tid = threadIdx.x;
    const int wv = tid >> 6, lane = tid & 63;
    const int l15 = lane & 15, l4 = lane >> 4;
    const int ar = tid >> 2, akq = (tid & 3) * 8;
    const int ga = bm + ar;

    f16x8 ra, rw[4];
    auto loadT = [&](int k0) {
        if (ga < M) ra = *reinterpret_cast<const f16x8*>(A + (size_t)ga * ldA + k0 + akq);
        else { f16x8 z = {}; ra = z; }
#pragma unroll
        for (int q = 0; q < 4; ++q)
            rw[q] = *reinterpret_cast<const f16x8*>(Wf + (size_t)(ar + 64 * q) * K + k0 + akq);
    };

    f32x4 acc[16];
#pragma unroll
    for (int c = 0; c < 16; ++c) acc[c] = (f32x4){0.f, 0.f, 0.f, 0.f};

    loadT(0);
    for (int k0 = 0; k0 < K; k0 += 32) {
        *reinterpret_cast<f16x8*>(&As[ar * PADK + akq]) = ra;
#pragma unroll
        for (int q = 0; q < 4; ++q)
            *reinterpret_cast<f16x8*>(&Ws[(ar + 64 * q) * PADK + akq]) = rw[q];
        __syncthreads();
        if (k0 + 32 < K) loadT(k0 + 32);
        f16x8 af = *reinterpret_cast<const f16x8*>(&As[(wv * 16 + l15) * PADK + l4 * 8]);
#pragma unroll
        for (int c = 0; c < 16; ++c) {
            f16x8 wf = *reinterpret_cast<const f16x8*>(&Ws[(c * 16 + l15) * PADK + l4 * 8]);
            acc[c] = __builtin_amdgcn_mfma_f32_16x16x32_f16(af, wf, acc[c], 0, 0, 0);
        }
        __syncthreads();
    }

#pragma unroll
    for (int c = 0; c < 16; ++c) {
        int gc = c * 16 + l15;
        float bv = (bias ? bias[gc] : 0.f) + (bias2 ? bias2[gc] : 0.f);
#pragma unroll
        for (int q = 0; q < 4; ++q) {
            int gr = bm + wv * 16 + l4 * 4 + q;
            if (gr >= M) continue;
            float v = acc[c][q] + bv;
            if (ACT == 1) v = lrelu_f(v);
            else if (ACT == 2) v = (v > 0.f ? v : expm1f(v));
            else if (ACT == 3) v = 1.f / (1.f + expf(-v));
            Cout[(size_t)gr * ldC + ocol + gc] = (_Float16)v;
        }
    }
}

template<int ACT>
__global__ __launch_bounds__(256, 4) void gemm16(
    const _Float16* __restrict__ A, const _Float16* __restrict__ Wf,
    const float* __restrict__ bias, _Float16* __restrict__ Cout,
    int M, int K, int ldA, int ldC, int ocol)
{
    __shared__ _Float16 As[64 * PADK];
    __shared__ _Float16 Ws[256 * PADK];
    gemm16_core<ACT>(As, Ws, A, Wf, bias, nullptr, Cout, M, K, ldA, ldC, ocol);
}

// GRU launch A: z=0/1: srz = sigmoid(Acat@wcat16^T + bih + bhh); z=2: inn = tmp@wihn16^T + bih_n
__global__ __launch_bounds__(256, 4) void gemm_gru_a16(
    const _Float16* __restrict__ Acat, const _Float16* __restrict__ wcat16,
    const _Float16* __restrict__ wihn16,
    const float* __restrict__ bih, const float* __restrict__ bhh,
    _Float16* __restrict__ srz, _Float16* __restrict__ innb, int mc)
{
    __shared__ _Float16 As[64 * PADK];
    __shared__ _Float16 Ws[256 * PADK];
    int z = blockIdx.z;
    if (z < 2)
        gemm16_core<3>(As, Ws, Acat, wcat16 + (size_t)z * 256 * 512, bih + z * 256, bhh + z * 256,
                       srz, mc, 512, LDC2, 512, z * 256);
    else
        gemm16_core<0>(As, Ws, Acat, wihn16, bih + 512, nullptr, innb, mc, 256, LDC2, 256, 0);
}

// GRU launch B: hn GEMM + in-epilogue GRU combine + ReLU (xcur in place) + fused dots
__global__ __launch_bounds__(256, 4) void gemm_gru_b16(
    _Float16* __restrict__ Acat, const _Float16* __restrict__ Wn16, const float* __restrict__ bhh,
    const _Float16* __restrict__ srz, const _Float16* __restrict__ innb,
    const float* __restrict__ us, const float* __restrict__ ud,
    float* __restrict__ dotr, float* __restrict__ adst, int mc)
{
    __shared__ _Float16 As[64 * PADK];
    __shared__ _Float16 Ws[256 * PADK];
    const int bm = blockIdx.y * 64;
    const int tid = threadIdx.x;
    const int wv = tid >> 6, lane = tid & 63;
    const int l15 = lane & 15, l4 = lane >> 4;
    const int ar = tid >> 2, akq = (tid & 3) * 8;
    const int ga = bm + ar;

    f16x8 ra, rw[4];
    auto loadT = [&](int k0) {
        if (ga < mc) ra = *reinterpret_cast<const f16x8*>(Acat + (size_t)ga * LDC2 + NH + k0 + akq);
        else { f16x8 z = {}; ra = z; }
#pragma unroll
        for (int q = 0; q < 4; ++q)
            rw[q] = *reinterpret_cast<const f16x8*>(Wn16 + (size_t)(ar + 64 * q) * NH + k0 + akq);
    };

    f32x4 acc[16];
#pragma unroll
    for (int c = 0; c < 16; ++c) acc[c] = (f32x4){0.f, 0.f, 0.f, 0.f};

    loadT(0);
    for (int k0 = 0; k0 < NH; k0 += 32) {
        *reinterpret_cast<f16x8*>(&As[ar * PADK + akq]) = ra;
#pragma unroll
        for (int q = 0; q < 4; ++q)
            *reinterpret_cast<f16x8*>(&Ws[(ar + 64 * q) * PADK + akq]) = rw[q];
        __syncthreads();
        if (k0 + 32 < NH) loadT(k0 + 32);
        f16x8 af = *reinterpret_cast<const f16x8*>(&As[(wv * 16 + l15) * PADK + l4 * 8]);
#pragma unroll
        for (int c = 0; c < 16; ++c) {
            f16x8 wf = *reinterpret_cast<const f16x8*>(&Ws[(c * 16 + l15) * PADK + l4 * 8]);
            acc[c] = __builtin_amdgcn_mfma_f32_16x16x32_f16(af, wf, acc[c], 0, 0, 0);
        }
        __syncthreads();
    }

    float pd1[4] = {0.f, 0.f, 0.f, 0.f};
    float pd2[4] = {0.f, 0.f, 0.f, 0.f};
#pragma unroll
    for (int c = 0; c < 16; ++c) {
        int gc = c * 16 + l15;
        float bhn = bhh[512 + gc];
        float usv = us ? us[gc] : 0.f;
        float udv = ud ? ud[gc] : 0.f;
#pragma unroll
        for (int q = 0; q < 4; ++q) {
            int gr = bm + wv * 16 + l4 * 4 + q;
            if (gr >= mc) continue;
            float hn = acc[c][q] + bhn;
            float rr = (float)srz[(size_t)gr * 512 + gc];
            float zz = (float)srz[(size_t)gr * 512 + 256 + gc];
            float inn = (float)innb[(size_t)gr * NH + gc];
            float nn = tanhf(inn + rr * hn);
            size_t xoff = (size_t)gr * LDC2 + NH + gc;
            float xold = (float)Acat[xoff];
            float hv = fmaxf((1.f - zz) * nn + zz * xold, 0.f);
            Acat[xoff] = (_Float16)hv;
            pd1[q] += hv * usv;
            pd2[q] += hv * udv;
        }
    }
    if (us) {
#pragma unroll
        for (int off = 1; off < 16; off <<= 1) {
#pragma unroll
            for (int q = 0; q < 4; ++q) {
                pd1[q] += __shfl_xor(pd1[q], off);
                pd2[q] += __shfl_xor(pd2[q], off);
            }
        }
        if (l15 == 0) {
#pragma unroll
            for (int q = 0; q < 4; ++q) {
                int gr = bm + wv * 16 + l4 * 4 + q;
                if (gr < mc) {
                    dotr[gr] = pd1[q];
                    if (ud) adst[gr] = pd2[q];
                }
            }
        }
    }
}

// ---------------- legacy f32-W MFMA GEMM (mol phase only) ----------------
template<int ACT, int OB, int AF16>
static __device__ __forceinline__ void gemm_core(
    _Float16* As, _Float16* Ws,
    const void* __restrict__ Av, const float* __restrict__ W,
    const float* __restrict__ bias, void* __restrict__ Cout,
    int M, int K, int Nout, int ldA, int ldW, int ldC, int ocol, int Kw, int bn)
{
    const int bm = blockIdx.y * 64;
    const int tid = threadIdx.x;
    const int wv = tid >> 6, lane = tid & 63;
    const int l15 = lane & 15, l4 = lane >> 4;
    const bool kvec = ((K & 31) == 0) && ((ldA & 3) == 0);
    const bool wvec = ((K & 31) == 0) && ((ldW & 3) == 0) && (Kw == K);
    const int ar = tid >> 2, akq = (tid & 3) * 8;

    f32x4 acc[16];
#pragma unroll
    for (int c = 0; c < 16; ++c) acc[c] = (f32x4){0.f, 0.f, 0.f, 0.f};

    for (int k0 = 0; k0 < K; k0 += 32) {
        {
            const int ga = bm + ar;
            _Float16* dstA = &As[ar * PADK + akq];
            if (AF16) {
                const _Float16* A = (const _Float16*)Av;
                if (ga < M) {
                    *reinterpret_cast<f16x8*>(dstA) =
                        *reinterpret_cast<const f16x8*>(A + (size_t)ga * ldA + k0 + akq);
                } else {
#pragma unroll
                    for (int j = 0; j < 8; ++j) dstA[j] = (_Float16)0.f;
                }
            } else {
                const float* A = (const float*)Av;
                if (ga < M && kvec) {
                    const float4* ap4 = reinterpret_cast<const float4*>(A + (size_t)ga * ldA + k0 + akq);
                    float4 v0 = ap4[0], v1 = ap4[1];
                    dstA[0] = (_Float16)v0.x; dstA[1] = (_Float16)v0.y;
                    dstA[2] = (_Float16)v0.z; dstA[3] = (_Float16)v0.w;
                    dstA[4] = (_Float16)v1.x; dstA[5] = (_Float16)v1.y;
                    dstA[6] = (_Float16)v1.z; dstA[7] = (_Float16)v1.w;
                } else {
                    const float* ap = A + (size_t)ga * ldA + k0 + akq;
#pragma unroll
                    for (int j = 0; j < 8; ++j) {
                        int gk = k0 + akq + j;
                        float v = (ga < M && gk < K) ? ap[j] : 0.f;
                        dstA[j] = (_Float16)v;
                    }
                }
            }
        }
#pragma unroll
        for (int q = 0; q < 4; ++q) {
            const int r = ar + 64 * q;
            const int gw = bn + r;
            _Float16* dstW = &Ws[r * PADK + akq];
            if (gw < Nout && wvec) {
                const float4* wp4 = reinterpret_cast<const float4*>(W + (size_t)gw * ldW + k0 + akq);
                float4 v0 = wp4[0], v1 = wp4[1];
                dstW[0] = (_Float16)v0.x; dstW[1] = (_Float16)v0.y;
                dstW[2] = (_Float16)v0.z; dstW[3] = (_Float16)v0.w;
                dstW[4] = (_Float16)v1.x; dstW[5] = (_Float16)v1.y;
                dstW[6] = (_Float16)v1.z; dstW[7] = (_Float16)v1.w;
            } else {
                const float* wp = W + (size_t)gw * ldW + k0 + akq;
#pragma unroll
                for (int j = 0; j < 8; ++j) {
                    int gk = k0 + akq + j;
                    float v = (gw < Nout && gk < Kw) ? wp[j] : 0.f;
                    dstW[j] = (_Float16)v;
                }
            }
        }
        __syncthreads();
        f16x8 af = *reinterpret_cast<const f16x8*>(&As[(wv * 16 + l15) * PADK + l4 * 8]);
#pragma unroll
        for (int c = 0; c < 16; ++c) {
            f16x8 wf = *reinterpret_cast<const f16x8*>(&Ws[(c * 16 + l15) * PADK + l4 * 8]);
            acc[c] = __builtin_amdgcn_mfma_f32_16x16x32_f16(af, wf, acc[c], 0, 0, 0);
        }
        __syncthreads();
    }

#pragma unroll
    for (int c = 0; c < 16; ++c) {
        int gc = bn + c * 16 + l15;
        if (gc >= Nout) continue;
        float bv = bias ? bias[gc] : 0.f;
#pragma unroll
        for (int q = 0; q < 4; ++q) {
            int gr = bm + wv * 16 + l4 * 4 + q;
            if (gr >= M) continue;
            float v = acc[c][q] + bv;
            if (ACT == 1) v = lrelu_f(v);
            else if (ACT == 2) v = (v > 0.f ? v : expm1f(v));
            size_t off = (size_t)gr * ldC + ocol + gc;
            if (OB) ((_Float16*)Cout)[off] = (_Float16)v;
            else    ((float*)Cout)[off] = v;
        }
    }
}

template<int ACT, int OB, int AF16>
__global__ __launch_bounds__(256, 4) void gemm_mfma(
    const void* __restrict__ A, const float* __restrict__ W,
    const float* __restrict__ bias, void* __restrict__ Cout,
    int M, int K, int Nout, int ldA, int ldW, int ldC, int ocol, int Kw)
{
    __shared__ _Float16 As[64 * PADK];
    __shared__ _Float16 Ws[256 * PADK];
    gemm_core<ACT, OB, AF16>(As, Ws, A, W, bias, Cout, M, K, Nout, ldA, ldW, ldC, ocol, Kw,
                             blockIdx.x * 256);
}

template<int ACT, int OB>
__global__ __launch_bounds__(256, 4) void gemm_mfma2(
    const float* __restrict__ A0, const float* __restrict__ A1,
    const float* __restrict__ W0, const float* __restrict__ W1,
    void* __restrict__ C0, void* __restrict__ C1, int M, int K, int Nout)
{
    __shared__ _Float16 As[64 * PADK];
    __shared__ _Float16 Ws[256 * PADK];
    int bn = blockIdx.x * 256;
    if (blockIdx.z == 0)
        gemm_core<ACT, OB, 0>(As, Ws, A0, W0, nullptr, C0, M, K, Nout, K, K, Nout, 0, K, bn);
    else
        gemm_core<ACT, OB, 0>(As, Ws, A1, W1, nullptr, C1, M, K, Nout, K, K, Nout, 0, K, bn);
}

// ---------------- weight conversion (one-time) ----------------
__global__ void cast_w16(const float* __restrict__ src, _Float16* __restrict__ dst,
                         int rows, int cols, int ldsrc, int kout)
{
    int i = blockIdx.x * 256 + threadIdx.x;
    if (i >= rows * kout) return;
    int r = i / kout, k = i % kout;
    dst[i] = (k < cols) ? (_Float16)src[(size_t)r * ldsrc + k] : (_Float16)0.f;
}
__global__ void build_wcat16(const float* __restrict__ wih, const float* __restrict__ whh,
                             _Float16* __restrict__ dst)
{
    int i = blockIdx.x * 256 + threadIdx.x;
    if (i >= 512 * 512) return;
    int j = i >> 9, k = i & 511;
    dst[i] = (_Float16)((k < 256) ? wih[j * 256 + k] : whh[j * 256 + (k - 256)]);
}

__global__ void pad_cast_f16(const float* __restrict__ in, _Float16* __restrict__ out,
                             int M, int Kin, int Kout)
{
    size_t i = (size_t)blockIdx.x * 256 + threadIdx.x;
    if (i >= (size_t)M * Kout) return;
    int r = (int)(i / Kout), k = (int)(i % Kout);
    out[i] = (k < Kin) ? (_Float16)in[(size_t)r * Kin + k] : (_Float16)0.f;
}

// ---------------- fp32 fallback GEMM (final 12-col fc only) ----------------
__global__ __launch_bounds__(256) void gemm_nt(
    const float* __restrict__ A, const float* __restrict__ W,
    const float* __restrict__ bias, float* __restrict__ C,
    int M, int K, int Nout, int ldW, int act)
{
    __shared__ float As[16][65];
    __shared__ float Ws[16][65];
    const int bm = blockIdx.y * 64;
    const int bn = blockIdx.x * 64;
    const int tid = threadIdx.x;
    const int tr = tid >> 4, tc = tid & 15;
    const int lrow = tid >> 2, lk = (tid & 3) * 4;
    float acc[4][4] = {};
    for (int k0 = 0; k0 < K; k0 += 16) {
#pragma unroll
        for (int j = 0; j < 4; ++j) {
            int gk = k0 + lk + j;
            int ga = bm + lrow;
            As[lk + j][lrow] = (ga < M && gk < K) ? A[(size_t)ga * K + gk] : 0.f;
            int gw = bn + lrow;
            Ws[lk + j][lrow] = (gw < Nout && gk < K) ? W[(size_t)gw * ldW + gk] : 0.f;
        }
        __syncthreads();
#pragma unroll
        for (int kk = 0; kk < 16; ++kk) {
            float av[4], bv[4];
#pragma unroll
            for (int i = 0; i < 4; ++i) av[i] = As[kk][tr * 4 + i];
#pragma unroll
            for (int i = 0; i < 4; ++i) bv[i] = Ws[kk][tc * 4 + i];
#pragma unroll
            for (int i = 0; i < 4; ++i)
#pragma unroll
                for (int j = 0; j < 4; ++j) acc[i][j] += av[i] * bv[j];
        }
        __syncthreads();
    }
#pragma unroll
    for (int i = 0; i < 4; ++i) {
        int m = bm + tr * 4 + i;
        if (m >= M) continue;
#pragma unroll
        for (int j = 0; j < 4; ++j) {
            int n = bn + tc * 4 + j;
            if (n >= Nout) continue;
            float v = acc[i][j];
            if (bias) v += bias[n];
            if (act == 1) v = lrelu_f(v);
            C[(size_t)m * Nout + n] = v;
        }
    }
}

// ---------------- CSR/CSC build ----------------
__global__ void zero_i32(int* p, int n) {
    int i = blockIdx.x * 256 + threadIdx.x;
    if (i < n) p[i] = 0;
}
__global__ void hist_k(const int* __restrict__ key, int* __restrict__ deg, int E) {
    int i = blockIdx.x * 256 + threadIdx.x;
    if (i < E) atomicAdd(&deg[key[i]], 1);
}
__global__ __launch_bounds__(256) void scan_pass1(
    const int* __restrict__ deg, int* __restrict__ bsum, int Nn)
{
    __shared__ int lds[256];
    int b = blockIdx.x, t = threadIdx.x;
    int base = b * SCAN_TILE + t * 8;
    int s = 0;
#pragma unroll
    for (int q = 0; q < 8; ++q) { int i = base + q; if (i < Nn) s += deg[i]; }
    lds[t] = s;
    __syncthreads();
    for (int off = 128; off; off >>= 1) {
        if (t < off) lds[t] += lds[t + off];
        __syncthreads();
    }
    if (t == 0) bsum[b] = lds[0];
}
__global__ __launch_bounds__(256) void scan_pass2(
    const int* __restrict__ bsum, int* __restrict__ boff, int nb, int* __restrict__ total)
{
    __shared__ int lds[256];
    int t = threadIdx.x;
    int v = (t < nb) ? bsum[t] : 0;
    lds[t] = v;
    __syncthreads();
    for (int off = 1; off < 256; off <<= 1) {
        int u = (t >= off) ? lds[t - off] : 0;
        __syncthreads();
        lds[t] += u;
        __syncthreads();
    }
    if (t < nb) boff[t] = lds[t] - v;
    if (t == 255 && total) *total = lds[255];
}
__global__ __launch_bounds__(256) void scan_pass3(
    const int* __restrict__ deg, const int* __restrict__ boff,
    int* __restrict__ rowptr, int* __restrict__ cursor, int Nn)
{
    __shared__ int lds[256];
    int b = blockIdx.x, t = threadIdx.x;
    int base = b * SCAN_TILE + t * 8;
    int v[8];
    int s = 0;
#pragma unroll
    for (int q = 0; q < 8; ++q) { int i = base + q; v[q] = (i < Nn) ? deg[i] : 0; s += v[q]; }
    lds[t] = s;
    __syncthreads();
    for (int off = 1; off < 256; off <<= 1) {
        int u = (t >= off) ? lds[t - off] : 0;
        __syncthreads();
        lds[t] += u;
        __syncthreads();
    }
    int run = boff[b] + lds[t] - s;
#pragma unroll
    for (int q = 0; q < 8; ++q) {
        int i = base + q;
        if (i < Nn) { rowptr[i] = run; cursor[i] = run; run += v[q]; }
    }
}
__global__ void csr_scatter(const int* __restrict__ src, const int* __restrict__ dst,
                            int* __restrict__ cursor, int* __restrict__ esrc,
                            int* __restrict__ pos, int E)
{
    int e = blockIdx.x * 256 + threadIdx.x;
    if (e < E) {
        int p = atomicAdd(&cursor[dst[e]], 1);
        esrc[p] = src[e];
        pos[e] = p;
    }
}
__global__ void csc_scatter(const int* __restrict__ src, int* __restrict__ cursor,
                            int* __restrict__ seid, int E)
{
    int e = blockIdx.x * 256 + threadIdx.x;
    if (e < E) {
        int p = atomicAdd(&cursor[src[e]], 1);
        seid[p] = e;
    }
}
__global__ void edge_csc_build(const float* __restrict__ edge_attr, const int* __restrict__ seid,
                               const int* __restrict__ pos, _Float16* __restrict__ ecsc,
                               int* __restrict__ pcsc, int E)
{
    int p = blockIdx.x * 256 + threadIdx.x;
    if (p >= E) return;
    int e = seid[p];
    pcsc[p] = pos[e];
    const float* ep = edge_attr + (size_t)e * FEDGE;
#pragma unroll
    for (int f = 0; f < FEDGE; ++f) ecsc[(size_t)p * 8 + f] = (_Float16)ep[f];
    ecsc[(size_t)p * 8 + 7] = (_Float16)0.f;
}
__global__ void gptr_build(const int* __restrict__ batch, int* __restrict__ gptr, int Nn, int G) {
    int g = blockIdx.x * 256 + threadIdx.x;
    if (g > G) return;
    int lo = 0, hi = Nn;
    while (lo < hi) { int mid = (lo + hi) >> 1; if (batch[mid] < g) lo = mid + 1; else hi = mid; }
    gptr[g] = lo;
}

// ---------------- GATE src-side partial logit (CSC, packed f16, 4-edge ILP) ----------------
__global__ __launch_bounds__(256) void gate_part_csc(
    const _Float16* __restrict__ nodepart, const _Float16* __restrict__ ecsc,
    const float* __restrict__ gate_lin1_w, const float* __restrict__ att_l,
    const int* __restrict__ srowptr, const int* __restrict__ pcsc,
    float* __restrict__ elogp, int Nn)
{
    int wv = threadIdx.x >> 6, lane = threadIdx.x & 63;
    int h0 = lane * 4;
    f16x2 wr2[2][FEDGE], al2[2];
#pragma unroll
    for (int p = 0; p < 2; ++p) {
        int ha = h0 + 2 * p, hb = ha + 1;
#pragma unroll
        for (int f = 0; f < FEDGE; ++f) {
            wr2[p][f][0] = (_Float16)gate_lin1_w[(size_t)ha * LDW_GATE1 + NH + f];
            wr2[p][f][1] = (_Float16)gate_lin1_w[(size_t)hb * LDW_GATE1 + NH + f];
        }
        al2[p][0] = (_Float16)att_l[ha];
        al2[p][1] = (_Float16)att_l[hb];
    }
    for (int s = blockIdx.x * 4 + wv; s < Nn; s += gridDim.x * 4) {
        int beg = srowptr[s], end = srowptr[s + 1];
        if (beg >= end) continue;
        f16x4 np4 = *reinterpret_cast<const f16x4*>(nodepart + (size_t)s * NH + h0);
        f16x2 np2[2];
        np2[0][0] = np4[0]; np2[0][1] = np4[1];
        np2[1][0] = np4[2]; np2[1][1] = np4[3];
        for (int j0 = beg; j0 < end; j0 += 4) {
            int nb = end - j0; if (nb > 4) nb = 4;
            f16x8 ev[4];
            int pp[4];
#pragma unroll
            for (int k = 0; k < 4; ++k) {
                int j = (k < nb) ? j0 + k : beg;
                pp[k] = pcsc[j];
                ev[k] = *reinterpret_cast<const f16x8*>(ecsc + (size_t)j * 8);
            }
            float acc[4];
#pragma unroll
            for (int k = 0; k < 4; ++k) {
                f16x2 v0 = np2[0], v1 = np2[1];
#pragma unroll
                for (int f = 0; f < FEDGE; ++f) {
                    f16x2 e2; e2[0] = ev[k][f]; e2[1] = ev[k][f];
                    v0 += e2 * wr2[0][f];
                    v1 += e2 * wr2[1][f];
                }
                float a = __builtin_amdgcn_fdot2(lrelu2(v0), al2[0], 0.f, false);
                a = __builtin_amdgcn_fdot2(lrelu2(v1), al2[1], a, false);
                acc[k] = a;
            }
#pragma unroll
            for (int off = 32; off; off >>= 1) {
#pragma unroll
                for (int k = 0; k < 4; ++k) acc[k] += __shfl_xor(acc[k], off);
            }
            if (lane == 0) {
#pragma unroll
                for (int k = 0; k < 4; ++k) if (k < nb) elogp[pp[k]] = acc[k];
            }
        }
    }
}

// ---------------- fused attention aggregation (CSR, wave per dst, LDS alpha cache) ----------------
__global__ __launch_bounds__(256) void gat_agg_csr(
    const _Float16* __restrict__ X, int ldX,
    const float* __restrict__ asrc, const float* __restrict__ adst,
    const int* __restrict__ rowptr, const int* __restrict__ esrc,
    _Float16* __restrict__ hout, int Nn)
{
    __shared__ float salpha[4][64];
    int wv = threadIdx.x >> 6, lane = threadIdx.x & 63;
    int d = blockIdx.x * 4 + wv;
    if (d >= Nn) return;
    int beg = rowptr[d], end = rowptr[d + 1];
    float a0 = 0.f, a1 = 0.f, a2 = 0.f, a3 = 0.f, ssum = 0.f;
    if (beg < end) {
        float ad = adst[d];
        float m = -3.4e38f;
        for (int j = beg + lane; j < end; j += 64)
            m = fmaxf(m, lrelu_f(asrc[esrc[j]] + ad));
#pragma unroll
        for (int off = 32; off; off >>= 1) m = fmaxf(m, __shfl_xor(m, off));
        for (int c0 = beg; c0 < end; c0 += 64) {
            int j = c0 + lane;
            float e = (j < end) ? expf(lrelu_f(asrc[esrc[j]] + ad) - m) : 0.f;
            salpha[wv][lane] = e;
            ssum += e;
            int cend = end - c0; if (cend > 64) cend = 64;
            for (int k = 0; k < cend; ++k) {
                float alk = salpha[wv][k];
                int sj = esrc[c0 + k];
                f16x4 xv = *reinterpret_cast<const f16x4*>(X + (size_t)sj * ldX + lane * 4);
                a0 += alk * (float)xv[0]; a1 += alk * (float)xv[1];
                a2 += alk * (float)xv[2]; a3 += alk * (float)xv[3];
            }
        }
#pragma unroll
        for (int off = 32; off; off >>= 1) ssum += __shfl_xor(ssum, off);
        float inv = 1.f / (ssum + 1e-16f);
        a0 *= inv; a1 *= inv; a2 *= inv; a3 *= inv;
    }
    f16x4 o;
    o[0] = (_Float16)a0; o[1] = (_Float16)a1; o[2] = (_Float16)a2; o[3] = (_Float16)a3;
    *reinterpret_cast<f16x4*>(hout + (size_t)d * NH + lane * 4) = o;
}

__global__ __launch_bounds__(256) void gate_agg_csr(
    const _Float16* __restrict__ X, int ldX,
    const float* __restrict__ elogp, const float* __restrict__ dotr,
    const int* __restrict__ rowptr, const int* __restrict__ esrc,
    _Float16* __restrict__ hout, int Nn)
{
    __shared__ float salpha[4][64];
    int wv = threadIdx.x >> 6, lane = threadIdx.x & 63;
    int d = blockIdx.x * 4 + wv;
    if (d >= Nn) return;
    int beg = rowptr[d], end = rowptr[d + 1];
    float a0 = 0.f, a1 = 0.f, a2 = 0.f, a3 = 0.f, ssum = 0.f;
    if (beg < end) {
        float dd = dotr[d];
        float m = -3.4e38f;
        for (int j = beg + lane; j < end; j += 64)
            m = fmaxf(m, lrelu_f(elogp[j] + dd));
#pragma unroll
        for (int off = 32; off; off >>= 1) m = fmaxf(m, __shfl_xor(m, off));
        for (int c0 = beg; c0 < end; c0 += 64) {
            int j = c0 + lane;
            float e = (j < end) ? expf(lrelu_f(elogp[j] + dd) - m) : 0.f;
            salpha[wv][lane] = e;
            ssum += e;
            int cend = end - c0; if (cend > 64) cend = 64;
            for (int k = 0; k < cend; ++k) {
                float alk = salpha[wv][k];
                int sj = esrc[c0 + k];
                f16x4 xv = *reinterpret_cast<const f16x4*>(X + (size_t)sj * ldX + lane * 4);
                a0 += alk * (float)xv[0]; a1 += alk * (float)xv[1];
                a2 += alk * (float)xv[2]; a3 += alk * (float)xv[3];
            }
        }
#pragma unroll
        for (int off = 32; off; off >>= 1) ssum += __shfl_xor(ssum, off);
        float inv = 1.f / (ssum + 1e-16f);
        a0 *= inv; a1 *= inv; a2 *= inv; a3 *= inv;
    }
    f16x4 o;
    o[0] = (_Float16)a0; o[1] = (_Float16)a1; o[2] = (_Float16)a2; o[3] = (_Float16)a3;
    *reinterpret_cast<f16x4*>(hout + (size_t)d * NH + lane * 4) = o;
}

__global__ __launch_bounds__(256) void mol_agg_csr(
    const _Float16* __restrict__ X, int ldX,
    const float* __restrict__ dotr, const float* __restrict__ ddot,
    const int* __restrict__ gptr, float* __restrict__ hout, int G)
{
    __shared__ float salpha[4][64];
    int wv = threadIdx.x >> 6, lane = threadIdx.x & 63;
    int g = blockIdx.x * 4 + wv;
    if (g >= G) return;
    int beg = gptr[g], end = gptr[g + 1];
    float a0 = 0.f, a1 = 0.f, a2 = 0.f, a3 = 0.f, ssum = 0.f;
    if (beg < end) {
        float dg = ddot[g];
        float m = -3.4e38f;
        for (int i = beg + lane; i < end; i += 64)
            m = fmaxf(m, lrelu_f(dotr[i] + dg));
#pragma unroll
        for (int off = 32; off; off >>= 1) m = fmaxf(m, __shfl_xor(m, off));
        for (int c0 = beg; c0 < end; c0 += 64) {
            int i = c0 + lane;
            float e = (i < end) ? expf(lrelu_f(dotr[i] + dg) - m) : 0.f;
            salpha[wv][lane] = e;
            ssum += e;
            int cend = end - c0; if (cend > 64) cend = 64;
            for (int k = 0; k < cend; ++k) {
                float alk = salpha[wv][k];
                f16x4 xv = *reinterpret_cast<const f16x4*>(X + (size_t)(c0 + k) * ldX + lane * 4);
                a0 += alk * (float)xv[0]; a1 += alk * (float)xv[1];
                a2 += alk * (float)xv[2]; a3 += alk * (float)xv[3];
            }
        }
#pragma unroll
        for (int off = 32; off; off >>= 1) ssum += __shfl_xor(ssum, off);
        float inv = 1.f / (ssum + 1e-16f);
        a0 *= inv; a1 *= inv; a2 *= inv; a3 *= inv;
    }
    float* hr = hout + (size_t)g * NH + lane * 4;
    hr[0] = a0; hr[1] = a1; hr[2] = a2; hr[3] = a3;
}

__global__ __launch_bounds__(256) void graph_sum_relu(
    const _Float16* __restrict__ X, int ldX, const int* __restrict__ gptr,
    float* __restrict__ out, int G)
{
    int wv = threadIdx.x >> 6, lane = threadIdx.x & 63;
    int g = blockIdx.x * 4 + wv;
    if (g >= G) return;
    int beg = gptr[g], end = gptr[g + 1];
    float a0 = 0.f, a1 = 0.f, a2 = 0.f, a3 = 0.f;
    for (int i = beg; i < end; ++i) {
        f16x4 xv = *reinterpret_cast<const f16x4*>(X + (size_t)i * ldX + lane * 4);
        a0 += (float)xv[0]; a1 += (float)xv[1]; a2 += (float)xv[2]; a3 += (float)xv[3];
    }
    float* hr = out + (size_t)g * NH + lane * 4;
    hr[0] = fmaxf(a0, 0.f); hr[1] = fmaxf(a1, 0.f);
    hr[2] = fmaxf(a2, 0.f); hr[3] = fmaxf(a3, 0.f);
}

template<typename TX>
__global__ __launch_bounds__(256) void node_dot(
    const TX* __restrict__ X, int ldX, const float* __restrict__ v1, const float* __restrict__ v2,
    float* __restrict__ o1, float* __restrict__ o2, int M)
{
    __shared__ float s1[NH], s2[NH];
    int tid = threadIdx.x;
    s1[tid] = v1[tid];
    s2[tid] = v2 ? v2[tid] : 0.f;
    __syncthreads();
    int wv = tid >> 6, lane = tid & 63;
    for (int n = blockIdx.x * 4 + wv; n < M; n += gridDim.x * 4) {
        float a1 = 0.f, a2 = 0.f;
#pragma unroll
        for (int i = 0; i < 4; ++i) {
            int hh = i * 64 + lane;
            float xv = (float)X[(size_t)n * ldX + hh];
            a1 += xv * s1[hh];
            a2 += xv * s2[hh];
        }
#pragma unroll
        for (int off = 32; off; off >>= 1) { a1 += __shfl_xor(a1, off); a2 += __shfl_xor(a2, off); }
        if (lane == 0) { o1[n] = a1; if (o2) o2[n] = a2; }
    }
}

__global__ __launch_bounds__(256) void matvec_left(
    const float* __restrict__ Wm, const float* __restrict__ a, float* __restrict__ v)
{
    int j = threadIdx.x;
    float s = 0.f;
    for (int i = 0; i < NH; ++i) s += a[i] * Wm[(size_t)i * NH + j];
    v[j] = s;
}

// mol GRU combine (f32 hprev/out), gi/gh f16 dense NH3
__global__ __launch_bounds__(256) void gru_combine(
    const _Float16* __restrict__ gi, const _Float16* __restrict__ gh,
    const float* __restrict__ b_ih, const float* __restrict__ b_hh,
    const float* __restrict__ hprev, float* __restrict__ out, int M)
{
    size_t t = (size_t)blockIdx.x * 256 + threadIdx.x;
    if (t >= (size_t)M * 32) return;
    int n = (int)(t >> 5), j0 = ((int)t & 31) * 8;
    size_t b3 = (size_t)n * NH3;
    f16x8 vir = *reinterpret_cast<const f16x8*>(&gi[b3 + j0]);
    f16x8 viz = *reinterpret_cast<const f16x8*>(&gi[b3 + NH + j0]);
    f16x8 vin = *reinterpret_cast<const f16x8*>(&gi[b3 + 2 * NH + j0]);
    f16x8 vhr = *reinterpret_cast<const f16x8*>(&gh[b3 + j0]);
    f16x8 vhz = *reinterpret_cast<const f16x8*>(&gh[b3 + NH + j0]);
    f16x8 vhn = *reinterpret_cast<const f16x8*>(&gh[b3 + 2 * NH + j0]);
    size_t hb = (size_t)n * NH + j0;
#pragma unroll
    for (int q = 0; q < 8; ++q) {
        int j = j0 + q;
        float r = 1.f / (1.f + expf(-((float)vir[q] + b_ih[j] + (float)vhr[q] + b_hh[j])));
        float z = 1.f / (1.f + expf(-((float)viz[q] + b_ih[NH + j] + (float)vhz[q] + b_hh[NH + j])));
        float nn = tanhf((float)vin[q] + b_ih[2 * NH + j] + r * ((float)vhn[q] + b_hh[2 * NH + j]));
        out[hb + q] = fmaxf((1.f - z) * nn + z * hprev[hb + q], 0.f);
    }
}

extern "C" void kernel_launch(void* const* d_in, const int* in_sizes, int n_in,
                              void* d_out, int out_size, void* d_ws, size_t ws_size,
                              hipStream_t stream)
{
    const float* x          = (const float*)d_in[0];
    const float* edge_attr  = (const float*)d_in[1];
    const float* lin1_w     = (const float*)d_in[2];
    const float* lin1_b     = (const float*)d_in[3];
    const float* gate_att_l = (const float*)d_in[4];
    const float* gate_att_r = (const float*)d_in[5];
    const float* gate_lin1_w= (const float*)d_in[6];
    const float* gate_lin2_w= (const float*)d_in[7];
    const float* gate_bias  = (const float*)d_in[8];
    const float* atom_lin_w = (const float*)d_in[9];
    const float* atom_att_src=(const float*)d_in[10];
    const float* atom_att_dst=(const float*)d_in[11];
    const float* atom_bias  = (const float*)d_in[12];
    const float* gru_w_ih   = (const float*)d_in[13];
    const float* gru_w_hh   = (const float*)d_in[14];
    const float* gru_b_ih   = (const float*)d_in[15];
    const float* gru_b_hh   = (const float*)d_in[16];
    const float* mol_lin_w  = (const float*)d_in[17];
    const float* mol_att_src= (const float*)d_in[18];
    const float* mol_att_dst= (const float*)d_in[19];
    const float* mol_bias   = (const float*)d_in[20];
    const float* mol_gru_w_ih=(const float*)d_in[21];
    const float* mol_gru_w_hh=(const float*)d_in[22];
    const float* mol_gru_b_ih=(const float*)d_in[23];
    const float* mol_gru_b_hh=(const float*)d_in[24];
    const float* lin2_w     = (const float*)d_in[25];
    const float* lin2_b     = (const float*)d_in[26];
    const float* fc_w       = (const float*)d_in[27];
    const float* fc_b       = (const float*)d_in[28];
    const int*   edge_index = (const int*)d_in[29];
    const int*   batch      = (const int*)d_in[30];

    const int N = in_sizes[0] / FNODE;
    const int E = in_sizes[1] / FEDGE;
    const int G = NGRAPH;
    const int* src = edge_index;
    const int* dst = edge_index + E;

    float* w = (float*)d_ws;
    size_t o = 0;
    auto alloc = [&](size_t cnt) { size_t r = o; o += cnt; return r; };
    const size_t o_B1cat = alloc((size_t)N * NH);          // f16 N x 512: [tmp | xcur]
    const size_t o_B2    = alloc((size_t)N * NH / 2);      // f16 nodepart -> hraw ; mol f32 bufs
    const size_t o_B3    = alloc((size_t)CHUNK * 512);     // inn+srz f16 ; xpad
    const size_t o_w16   = alloc((size_t)972000);          // f16 weight pool
    const size_t o_elog  = alloc((size_t)E);
    const size_t o_dotr  = alloc((size_t)N);
    const size_t o_adst  = alloc((size_t)N);
    const size_t o_ddot  = alloc((size_t)G);
    const size_t o_vvec  = alloc((size_t)NH);
    const size_t o_usrc  = alloc((size_t)NH);
    const size_t o_udst  = alloc((size_t)NH);
    const size_t o_rowp  = alloc((size_t)N + 1);
    const size_t o_srowp = alloc((size_t)N + 1);
    const size_t o_deg   = alloc((size_t)N);
    const size_t o_curs  = alloc((size_t)N);
    const size_t o_bsum  = alloc((size_t)512);
    const size_t o_esrc  = alloc((size_t)E);
    const size_t o_pos   = alloc((size_t)E);
    const size_t o_seid  = alloc((size_t)E);
    const size_t o_ecsc  = alloc((size_t)E * 4);
    const size_t o_pcsc  = alloc((size_t)E);
    const size_t o_gptr  = alloc((size_t)G + 1);
    if (o * sizeof(float) > ws_size) {
        fprintf(stderr, "kernel_launch: ws too small: need %zu have %zu\n", o * 4, ws_size);
        return;
    }

    _Float16* B1cat = (_Float16*)(w + o_B1cat);
    _Float16* xcur  = B1cat + NH;
    _Float16* B2 = (_Float16*)(w + o_B2);
    float* B3   = w + o_B3;
    _Float16* w16 = (_Float16*)(w + o_w16);
    _Float16* lin116   = w16;                       // 256*160
    _Float16* gate1a16 = lin116 + 40960;            // 256*256
    _Float16* gate216  = gate1a16 + 65536;          // 256*256
    _Float16* atom16   = gate216 + 65536;           // 3 * 65536
    _Float16* wihn16   = atom16 + 3 * 65536;        // 4 * 65536
    _Float16* whhn16   = wihn16 + 4 * 65536;        // 4 * 65536
    _Float16* wcat16   = whhn16 + 4 * 65536;        // 4 * 262144
    float* elog = w + o_elog;
    float* dotr = w + o_dotr;
    float* adst = w + o_adst;
    float* ddot = w + o_ddot;
    float* vvec = w + o_vvec;
    float* usrc = w + o_usrc;
    float* udst = w + o_udst;
    int* rowptr  = (int*)(w + o_rowp);
    int* srowptr = (int*)(w + o_srowp);
    int* deg     = (int*)(w + o_deg);
    int* cursor  = (int*)(w + o_curs);
    int* bsum    = (int*)(w + o_bsum);
    int* boff    = bsum + 256;
    int* esrc    = (int*)(w + o_esrc);
    int* pos     = (int*)(w + o_pos);
    int* seid    = (int*)(w + o_seid);
    _Float16* ecsc = (_Float16*)(w + o_ecsc);
    int* pcsc    = (int*)(w + o_pcsc);
    int* gptr    = (int*)(w + o_gptr);

    // mol-phase f32 sub-buffers inside B2
    float* B2f = (float*)B2;
    float*    gout   = B2f;
    float*    hraw_g = B2f + (size_t)G * NH;
    float*    h_g    = B2f + (size_t)2 * G * NH;
    _Float16* gig    = (_Float16*)(B2f + (size_t)3 * G * NH);
    _Float16* ghg    = (_Float16*)(B2f + (size_t)3 * G * NH + (size_t)G * NH3 / 2);
    float*    emb    = B2f + (size_t)3 * G * NH + (size_t)G * NH3;

    const int BLK = 256;
    auto cdiv = [](size_t a, size_t b) { return (int)((a + b - 1) / b); };
    const int gridNodeWave = cdiv(N, 4);
    const int gridEdgeThr = cdiv(E, BLK);
    const int gridNodeThr = cdiv(N, BLK);
    const int CAP = 4096;
    const int gridNodeCap = gridNodeWave < CAP ? gridNodeWave : CAP;
    const int nScanB = cdiv(N, SCAN_TILE);

    auto run_scan = [&](int* rowp) {
        scan_pass1<<<nScanB, BLK, 0, stream>>>(deg, bsum, N);
        scan_pass2<<<1, BLK, 0, stream>>>(bsum, boff, nScanB, rowp + N);
        scan_pass3<<<nScanB, BLK, 0, stream>>>(deg, boff, rowp, cursor, N);
    };

    // ---------- weight conversion (one-time) ----------
    cast_w16<<<cdiv(256 * 160, BLK), BLK, 0, stream>>>(lin1_w, lin116, 256, FNODE, FNODE, 160);
    cast_w16<<<cdiv(65536, BLK), BLK, 0, stream>>>(gate_lin1_w, gate1a16, 256, 256, LDW_GATE1, 256);
    cast_w16<<<cdiv(65536, BLK), BLK, 0, stream>>>(gate_lin2_w, gate216, 256, 256, 256, 256);
    for (int l = 0; l < 3; ++l)
        cast_w16<<<cdiv(65536, BLK), BLK, 0, stream>>>(atom_lin_w + (size_t)l * 65536,
                                                       atom16 + (size_t)l * 65536, 256, 256, 256, 256);
    for (int l = 0; l < 4; ++l) {
        const float* wih = gru_w_ih + (size_t)l * NH3 * NH;
        const float* whh = gru_w_hh + (size_t)l * NH3 * NH;
        build_wcat16<<<1024, BLK, 0, stream>>>(wih, whh, wcat16 + (size_t)l * 262144);
        cast_w16<<<cdiv(65536, BLK), BLK, 0, stream>>>(wih + 512 * NH, wihn16 + (size_t)l * 65536,
                                                       256, 256, 256, 256);
        cast_w16<<<cdiv(65536, BLK), BLK, 0, stream>>>(whh + 512 * NH, whhn16 + (size_t)l * 65536,
                                                       256, 256, 256, 256);
    }

    // ---------- CSR + CSC build (once) ----------
    zero_i32<<<gridNodeThr, BLK, 0, stream>>>(deg, N);
    hist_k<<<gridEdgeThr, BLK, 0, stream>>>(dst, deg, E);
    run_scan(rowptr);
    csr_scatter<<<gridEdgeThr, BLK, 0, stream>>>(src, dst, cursor, esrc, pos, E);
    zero_i32<<<gridNodeThr, BLK, 0, stream>>>(deg, N);
    hist_k<<<gridEdgeThr, BLK, 0, stream>>>(src, deg, E);
    run_scan(srowptr);
    csc_scatter<<<gridEdgeThr, BLK, 0, stream>>>(src, cursor, seid, E);
    edge_csc_build<<<gridEdgeThr, BLK, 0, stream>>>(edge_attr, seid, pos, ecsc, pcsc, E);
    gptr_build<<<cdiv(G + 1, BLK), BLK, 0, stream>>>(batch, gptr, N, G);

    // Per-layer tail
    auto run_tail = [&](const _Float16* Wh16, const float* bh, int l,
                        const float* bih, const float* bhh,
                        const float* usv, const float* udv) {
        _Float16* innb = (_Float16*)B3;                 // CHUNK*256 f16
        _Float16* srz  = innb + (size_t)CHUNK * NH;     // CHUNK*512 f16
        dim3 gFull(1, cdiv(N, 64));
        gemm16<2><<<gFull, BLK, 0, stream>>>(B2, Wh16, bh, B1cat, N, NH, NH, LDC2, 0);
        for (int c0 = 0; c0 < N; c0 += CHUNK) {
            int mc = (N - c0) < CHUNK ? (N - c0) : CHUNK;
            dim3 gA(1, cdiv(mc, 64), 3);
            gemm_gru_a16<<<gA, BLK, 0, stream>>>(B1cat + (size_t)c0 * LDC2,
                                                 wcat16 + (size_t)l * 262144,
                                                 wihn16 + (size_t)l * 65536,
                                                 bih, bhh, srz, innb, mc);
            dim3 gB(1, cdiv(mc, 64));
            gemm_gru_b16<<<gB, BLK, 0, stream>>>(B1cat + (size_t)c0 * LDC2,
                                                 whhn16 + (size_t)l * 65536, bhh,
                                                 srz, innb, usv, udv, dotr + c0, adst + c0, mc);
        }
    };

    dim3 gridNH(1, cdiv(N, 64));

    // ---------- x0 = lrelu(x @ lin1^T + b) -> xcur ----------
    _Float16* xpad = (_Float16*)B3;
    pad_cast_f16<<<cdiv((size_t)N * KPAD_X, BLK), BLK, 0, stream>>>(x, xpad, N, FNODE, KPAD_X);
    gemm16<1><<<gridNH, BLK, 0, stream>>>(xpad, lin116, lin1_b, B1cat, N, KPAD_X, KPAD_X, LDC2, NH);

    // ---------- GATEConv ----------
    gemm16<0><<<gridNH, BLK, 0, stream>>>(xcur, gate1a16, nullptr, B2, N, NH, LDC2, NH, 0);
    node_dot<_Float16><<<gridNodeCap, BLK, 0, stream>>>(xcur, LDC2, gate_att_r, nullptr,
                                                        dotr, nullptr, N);
    gate_part_csc<<<gridNodeCap, BLK, 0, stream>>>(B2, ecsc, gate_lin1_w, gate_att_l,
                                                   srowptr, pcsc, elog, N);
    gate_agg_csr<<<gridNodeWave, BLK, 0, stream>>>(xcur, LDC2, elog, dotr, rowptr, esrc, B2, N);
    matvec_left<<<1, BLK, 0, stream>>>(atom_lin_w, atom_att_src, usrc);
    matvec_left<<<1, BLK, 0, stream>>>(atom_lin_w, atom_att_dst, udst);
    run_tail(gate216, gate_bias, 0, gru_b_ih, gru_b_hh, usrc, udst);

    // ---------- 3 GATConv layers ----------
    for (int l = 0; l < 3; ++l) {
        gat_agg_csr<<<gridNodeWave, BLK, 0, stream>>>(xcur, LDC2, dotr, adst, rowptr, esrc, B2, N);
        const float* nus = usrc;
        const float* nud = udst;
        if (l < 2) {
            matvec_left<<<1, BLK, 0, stream>>>(atom_lin_w + (size_t)(l + 1) * NH * NH,
                                               atom_att_src + (l + 1) * NH, usrc);
            matvec_left<<<1, BLK, 0, stream>>>(atom_lin_w + (size_t)(l + 1) * NH * NH,
                                               atom_att_dst + (l + 1) * NH, udst);
        } else {
            matvec_left<<<1, BLK, 0, stream>>>(mol_lin_w, mol_att_src, usrc);
            nud = nullptr;
        }
        run_tail(atom16 + (size_t)l * 65536, atom_bias + l * NH, l + 1,
                 gru_b_ih + (size_t)(l + 1) * NH3, gru_b_hh + (size_t)(l + 1) * NH3, nus, nud);
    }

    // ---------- Molecule pooling ----------
    const int gridGWave = cdiv(G, 4);
    graph_sum_relu<<<gridGWave, BLK, 0, stream>>>(xcur, LDC2, gptr, gout, G);
    matvec_left<<<1, BLK, 0, stream>>>(mol_lin_w, mol_att_dst, vvec);

    dim3 gridGH(1, cdiv(G, 64));
    dim3 gridGD(3, cdiv(G, 64), 2);
    for (int t = 0; t < 2; ++t) {
        node_dot<float><<<gridGWave, BLK, 0, stream>>>(gout, NH, vvec, nullptr, ddot, nullptr, G);
        mol_agg_csr<<<gridGWave, BLK, 0, stream>>>(xcur, LDC2, dotr, ddot, gptr, hraw_g, G);
        gemm_mfma<2, 0, 0><<<gridGH, BLK, 0, stream>>>(hraw_g, mol_lin_w, mol_bias, h_g,
                                                       G, NH, NH, NH, NH, NH, 0, NH);
        gemm_mfma2<0, 1><<<gridGD, BLK, 0, stream>>>(h_g, gout, mol_gru_w_ih, mol_gru_w_hh,
                                                     gig, ghg, G, NH, NH3);
        gru_combine<<<cdiv((size_t)G * 32, BLK), BLK, 0, stream>>>(
            gig, ghg, mol_gru_b_ih, mol_gru_b_hh, gout, gout, G);
    }

    // ---------- readout ----------
    gemm_mfma<0, 0, 0><<<gridGH, BLK, 0, stream>>>(gout, lin2_w, lin2_b, emb,
                                                   G, NH, NH, NH, NH, NH, 0, NH);
    dim3 gridFc(1, cdiv(G, 64));
    gemm_nt<<<gridFc, BLK, 0, stream>>>(emb, fc_w, fc_b, (float*)d_out, G, NH, NTASK, NH, 0);
}